// Round 13
// baseline (981.091 us; speedup 1.0000x reference)
//
#include <hip/hip_runtime.h>
#include <hip/hip_bf16.h>
#include <math.h>

#define N_NODES 40000
#define N_EDGES 640000
#define F_IN    15
#define HID     128
#define NLAYERS 4
#define NOUT    21

#define FLAG_BIAS 1
#define FLAG_ACC  2
#define FLAG_SILU 4

typedef __attribute__((ext_vector_type(8))) short bf16x8;
typedef __attribute__((ext_vector_type(16))) float f32x16;
typedef __attribute__((ext_vector_type(2)))  float vf2;

__device__ __forceinline__ float silu_f(float x) {
    return x * __builtin_amdgcn_rcpf(1.0f + __expf(-x));
}

__device__ __forceinline__ unsigned short f2bf(float f) {
    unsigned u = __builtin_bit_cast(unsigned, f);
    unsigned r = (u + 0x7FFFu + ((u >> 16) & 1u)) >> 16;
    return (unsigned short)r;
}
__device__ __forceinline__ float bf2f(unsigned short b) {
    return __builtin_bit_cast(float, (unsigned)b << 16);
}

__device__ __forceinline__ void split2v(vf2 v, unsigned& hi2, unsigned& lo2) {
    union { __hip_bfloat162 b; unsigned u; } ch, cl;
    ch.b = __float22bfloat162_rn(make_float2(v.x, v.y));
    vf2 h;
    h.x = __builtin_bit_cast(float, ch.u << 16);
    h.y = __builtin_bit_cast(float, ch.u & 0xFFFF0000u);
    vf2 r = v - h;
    cl.b = __float22bfloat162_rn(make_float2(r.x, r.y));
    hi2 = ch.u;
    lo2 = cl.u;
}

__device__ __forceinline__ void store_split(char* a_hi, char* a_lo, int row, int col, float v) {
    unsigned short h = f2bf(v);
    unsigned short l = f2bf(v - bf2f(h));
    int byte = (row * 256 + col * 2) ^ ((row & 7) << 4);
    *(unsigned short*)(a_hi + byte) = h;
    *(unsigned short*)(a_lo + byte) = l;
}

// ---------------- radial ----------------
__global__ __launch_bounds__(256) void radial_kernel(
    const float* __restrict__ x, const int* __restrict__ erow,
    const int* __restrict__ ecol, float* __restrict__ radial)
{
    int e = blockIdx.x * 256 + threadIdx.x;
    if (e >= N_EDGES) return;
    int r = erow[e], c = ecol[e];
    float dx = x[r*3+0] - x[c*3+0];
    float dy = x[r*3+1] - x[c*3+1];
    float dz = x[r*3+2] - x[c*3+2];
    radial[e] = dx*dx + dy*dy + dz*dz;
}

// ---------------- CSR build ----------------
__global__ __launch_bounds__(256) void hist_kernel(
    const int* __restrict__ erow, int* __restrict__ cnt)
{
    int e = blockIdx.x * 256 + threadIdx.x;
    if (e < N_EDGES) atomicAdd(&cnt[erow[e]], 1);
}

__global__ __launch_bounds__(1024) void scan_kernel(
    const int* __restrict__ cnt, int* __restrict__ rowptr)
{
    __shared__ int s[1024];
    __shared__ int carry_s;
    const int tid = threadIdx.x;
    if (tid == 0) { carry_s = 0; rowptr[0] = 0; }
    __syncthreads();
    for (int base = 0; base < N_NODES; base += 1024) {
        int i = base + tid;
        int v = (i < N_NODES) ? cnt[i] : 0;
        s[tid] = v;
        __syncthreads();
        for (int off = 1; off < 1024; off <<= 1) {
            int t = (tid >= off) ? s[tid - off] : 0;
            __syncthreads();
            s[tid] += t;
            __syncthreads();
        }
        int c = carry_s;
        if (i < N_NODES) rowptr[i + 1] = c + s[tid];
        __syncthreads();
        if (tid == 1023) carry_s = c + s[1023];
        __syncthreads();
    }
}

__global__ __launch_bounds__(256) void scatter_kernel(
    const int* __restrict__ erow, const int* __restrict__ ecol,
    const float* __restrict__ radial, const float* __restrict__ edge_attr,
    const int* __restrict__ rowptr, int* __restrict__ fill,
    int* __restrict__ srow, int* __restrict__ scol,
    float* __restrict__ srad, float* __restrict__ sea)
{
    int e = blockIdx.x * 256 + threadIdx.x;
    if (e >= N_EDGES) return;
    int r = erow[e];
    int pos = rowptr[r] + atomicAdd(&fill[r], 1);
    srow[pos] = r;
    scol[pos] = ecol[e];
    srad[pos] = radial[e];
    float4 ea = *(const float4*)&edge_attr[(size_t)e * 4];
    *(float4*)&sea[(size_t)pos * 4] = ea;
}

// ---------------- unified weight split/transpose prep ----------------
#define OFF_W2   0
#define OFF_W1A  65536
#define OFF_W1B  131072
#define OFF_NW1  196608
#define OFF_NW2  335872
#define OFF_DW1  401408
#define OFF_DW2  417792
#define OFF_GW1  434176
#define W_TOTAL  450560

__global__ __launch_bounds__(256) void prep_all_kernel(
    const float* __restrict__ ew1, const float* __restrict__ ew2,
    const float* __restrict__ nw1, const float* __restrict__ nw2,
    const float* __restrict__ dw1, const float* __restrict__ dw2,
    const float* __restrict__ gw1,
    unsigned short* __restrict__ hi, unsigned short* __restrict__ lo)
{
    const int T = blockIdx.y;
    int srcSel, srcOff, K, dstOff;
    if (T < 4)       { srcSel=1; srcOff=T*16384;           K=128; dstOff=OFF_W2 +T*16384; }
    else if (T < 8)  { int l=T-4;  srcSel=0; srcOff=l*33408;        K=128; dstOff=OFF_W1A+l*16384; }
    else if (T < 12) { int l=T-8;  srcSel=0; srcOff=l*33408+16384;  K=128; dstOff=OFF_W1B+l*16384; }
    else if (T < 16) { int l=T-12; srcSel=2; srcOff=l*34688;        K=271; dstOff=OFF_NW1+l*34816; }
    else if (T < 20) { int l=T-16; srcSel=3; srcOff=l*16384;        K=128; dstOff=OFF_NW2+l*16384; }
    else if (T == 20){ srcSel=4; srcOff=0; K=128; dstOff=OFF_DW1; }
    else if (T == 21){ srcSel=5; srcOff=0; K=128; dstOff=OFF_DW2; }
    else             { srcSel=6; srcOff=0; K=128; dstOff=OFF_GW1; }

    const float* src;
    switch (srcSel) {
        case 0: src = ew1; break;  case 1: src = ew2; break;
        case 2: src = nw1; break;  case 3: src = nw2; break;
        case 4: src = dw1; break;  case 5: src = dw2; break;
        default: src = gw1; break;
    }
    int K16 = (K + 15) & ~15;
    int idx = blockIdx.x * 256 + threadIdx.x;
    if (idx >= K16 * 128) return;
    int k = idx >> 7, c = idx & 127;
    float v = (k < K) ? src[srcOff + k * 128 + c] : 0.0f;
    unsigned short h = f2bf(v);
    unsigned short lw = f2bf(v - bf2f(h));
    int o = dstOff + ((k >> 3) << 10) + (c << 3) + (k & 7);
    hi[o] = h; lo[o] = lw;
}

// ---------------- generic fp32 GEMM (32-row tile): emb (K=15), gw2 (J=21) --
__global__ __launch_bounds__(256) void gemm_kernel(
    const float* __restrict__ A, int lda,
    const float* __restrict__ W, int ldw,
    const float* __restrict__ bias,
    float* __restrict__ out, int ldout,
    int M, int K, int J, int flags)
{
    __shared__ float s_a[32 * 132];
    const int tid = threadIdx.x;
    const int row0 = blockIdx.x * 32;

    for (int idx = tid; idx < 32 * K; idx += 256) {
        int r = (K == 128) ? (idx >> 7) : (idx / K);
        int k = idx - r * K;
        int gr = row0 + r;
        s_a[r * 132 + k] = (gr < M) ? A[(size_t)gr * lda + k] : 0.0f;
    }
    __syncthreads();

    const int jg = tid & 31;
    const int rg = tid >> 5;
    const int j  = jg * 4;
    const int r0 = rg * 4;

    float acc[4][4] = {};

    if (j < J) {
        const bool w4ok = ((ldw & 3) == 0) && (j + 4 <= J);
        int k = 0;
        for (; k + 4 <= K; k += 4) {
            float4 av[4];
            #pragma unroll
            for (int i = 0; i < 4; i++)
                av[i] = *(const float4*)&s_a[(r0 + i) * 132 + k];
            #pragma unroll
            for (int kk = 0; kk < 4; kk++) {
                const float* wp = W + (size_t)(k + kk) * ldw + j;
                float4 w4;
                if (w4ok) {
                    w4 = *(const float4*)wp;
                } else {
                    w4.x = (j + 0 < J) ? wp[0] : 0.0f;
                    w4.y = (j + 1 < J) ? wp[1] : 0.0f;
                    w4.z = (j + 2 < J) ? wp[2] : 0.0f;
                    w4.w = (j + 3 < J) ? wp[3] : 0.0f;
                }
                #pragma unroll
                for (int i = 0; i < 4; i++) {
                    float a = ((const float*)&av[i])[kk];
                    acc[i][0] += a * w4.x;
                    acc[i][1] += a * w4.y;
                    acc[i][2] += a * w4.z;
                    acc[i][3] += a * w4.w;
                }
            }
        }
        for (; k < K; k++) {
            const float* wp = W + (size_t)k * ldw + j;
            float w0 = (j + 0 < J) ? wp[0] : 0.0f;
            float w1 = (j + 1 < J) ? wp[1] : 0.0f;
            float w2 = (j + 2 < J) ? wp[2] : 0.0f;
            float w3 = (j + 3 < J) ? wp[3] : 0.0f;
            #pragma unroll
            for (int i = 0; i < 4; i++) {
                float a = s_a[(r0 + i) * 132 + k];
                acc[i][0] += a * w0;
                acc[i][1] += a * w1;
                acc[i][2] += a * w2;
                acc[i][3] += a * w3;
            }
        }
    }

    #pragma unroll
    for (int i = 0; i < 4; i++) {
        int gr = row0 + r0 + i;
        if (gr >= M) continue;
        #pragma unroll
        for (int t = 0; t < 4; t++) {
            int jj = j + t;
            if (jj >= J) continue;
            float v = acc[i][t];
            if (flags & FLAG_BIAS) v += bias[jj];
            if (flags & FLAG_ACC)  v += out[(size_t)gr * ldout + jj];
            if (flags & FLAG_SILU) v = silu_f(v);
            out[(size_t)gr * ldout + jj] = v;
        }
    }
}

// ---------------- shared MFMA helpers ----------------
__device__ __forceinline__ void stage_a_chunk(
    char* a_hi, char* a_lo,
    const float* __restrict__ A1, int lda1, int KA1,
    const float* __restrict__ A2, int lda2, int KA,
    int kc, int row0, int lane, int w)
{
    if (kc + 128 <= KA1) {
        #pragma unroll 4
        for (int it = 0; it < 16; ++it) {
            int row = it * 4 + w;
            vf2 v = *(const vf2*)&A1[(size_t)(row0 + row) * lda1 + kc + lane * 2];
            unsigned hi2, lo2;
            split2v(v, hi2, lo2);
            int byte = (row * 256 + lane * 4) ^ ((row & 7) << 4);
            *(unsigned*)(a_hi + byte) = hi2;
            *(unsigned*)(a_lo + byte) = lo2;
        }
    } else {
        for (int it = 0; it < 16; ++it) {
            int row = it * 4 + w;
            vf2 vv;
            #pragma unroll
            for (int d = 0; d < 2; ++d) {
                int k = kc + lane * 2 + d;
                float v = 0.0f;
                if (k < KA1) v = A1[(size_t)(row0 + row) * lda1 + k];
                else if (k < KA) v = A2[(size_t)(row0 + row) * lda2 + (k - KA1)];
                vv[d] = v;
            }
            unsigned hi2, lo2;
            split2v(vv, hi2, lo2);
            int byte = (row * 256 + lane * 4) ^ ((row & 7) << 4);
            *(unsigned*)(a_hi + byte) = hi2;
            *(unsigned*)(a_lo + byte) = lo2;
        }
    }
}

__device__ __forceinline__ void mfma_chunk(
    const char* a_hi, const char* a_lo,
    const unsigned short* __restrict__ bhi, const unsigned short* __restrict__ blo,
    int kc, int nks, int lid, int khalf, int colw,
    f32x16& acc0, f32x16& acc1)
{
    const int sw0 = (lid & 7) << 4;
    for (int ks = 0; ks < nks; ++ks) {
        int ab = (lid * 256 + ks * 32 + khalf * 16) ^ sw0;
        bf16x8 ah0 = *(const bf16x8*)(a_hi + ab);
        bf16x8 al0 = *(const bf16x8*)(a_lo + ab);
        bf16x8 ah1 = *(const bf16x8*)(a_hi + ab + 8192);
        bf16x8 al1 = *(const bf16x8*)(a_lo + ab + 8192);
        int slot = (kc >> 3) + (ks << 1) + khalf;
        bf16x8 bh = *(const bf16x8*)(bhi + (slot << 10) + (colw << 3));
        bf16x8 bl = *(const bf16x8*)(blo + (slot << 10) + (colw << 3));
        acc0 = __builtin_amdgcn_mfma_f32_32x32x16_bf16(ah0, bh, acc0, 0, 0, 0);
        acc1 = __builtin_amdgcn_mfma_f32_32x32x16_bf16(ah1, bh, acc1, 0, 0, 0);
        acc0 = __builtin_amdgcn_mfma_f32_32x32x16_bf16(ah0, bl, acc0, 0, 0, 0);
        acc1 = __builtin_amdgcn_mfma_f32_32x32x16_bf16(ah1, bl, acc1, 0, 0, 0);
        acc0 = __builtin_amdgcn_mfma_f32_32x32x16_bf16(al0, bh, acc0, 0, 0, 0);
        acc1 = __builtin_amdgcn_mfma_f32_32x32x16_bf16(al1, bh, acc1, 0, 0, 0);
    }
}

// ---------------- merged projection kernel (layer 0 only) ----------------
__global__ __launch_bounds__(256) void mfma_proj_kernel(
    const float* __restrict__ hb,
    const unsigned short* __restrict__ wahi, const unsigned short* __restrict__ walo,
    const unsigned short* __restrict__ wbhi, const unsigned short* __restrict__ wblo,
    const float* __restrict__ b1, float* __restrict__ P, float* __restrict__ hbw)
{
    __shared__ char a_hi[16384];
    __shared__ char a_lo[16384];

    const int tid   = threadIdx.x;
    const int lane  = tid & 63;
    const int w     = tid >> 6;
    const int row0  = blockIdx.x * 64;
    const int lid   = lane & 31;
    const int khalf = lane >> 5;
    const int colw  = (w << 5) + lid;

    stage_a_chunk(a_hi, a_lo, hb, 256, 128, nullptr, 0, 128, 0, row0, lane, w);
    __syncthreads();

    f32x16 aA0, aA1, aB0, aB1;
    #pragma unroll
    for (int i = 0; i < 16; ++i) { aA0[i]=0.f; aA1[i]=0.f; aB0[i]=0.f; aB1[i]=0.f; }

    const int sw0 = (lid & 7) << 4;
    #pragma unroll 2
    for (int ks = 0; ks < 8; ++ks) {
        int ab = (lid * 256 + ks * 32 + khalf * 16) ^ sw0;
        bf16x8 ah0 = *(const bf16x8*)(a_hi + ab);
        bf16x8 al0 = *(const bf16x8*)(a_lo + ab);
        bf16x8 ah1 = *(const bf16x8*)(a_hi + ab + 8192);
        bf16x8 al1 = *(const bf16x8*)(a_lo + ab + 8192);
        int slot = (ks << 1) + khalf;
        bf16x8 bah = *(const bf16x8*)(wahi + (slot << 10) + (colw << 3));
        bf16x8 bal = *(const bf16x8*)(walo + (slot << 10) + (colw << 3));
        bf16x8 bbh = *(const bf16x8*)(wbhi + (slot << 10) + (colw << 3));
        bf16x8 bbl = *(const bf16x8*)(wblo + (slot << 10) + (colw << 3));
        aA0 = __builtin_amdgcn_mfma_f32_32x32x16_bf16(ah0, bah, aA0, 0, 0, 0);
        aA1 = __builtin_amdgcn_mfma_f32_32x32x16_bf16(ah1, bah, aA1, 0, 0, 0);
        aB0 = __builtin_amdgcn_mfma_f32_32x32x16_bf16(ah0, bbh, aB0, 0, 0, 0);
        aB1 = __builtin_amdgcn_mfma_f32_32x32x16_bf16(ah1, bbh, aB1, 0, 0, 0);
        aA0 = __builtin_amdgcn_mfma_f32_32x32x16_bf16(ah0, bal, aA0, 0, 0, 0);
        aA1 = __builtin_amdgcn_mfma_f32_32x32x16_bf16(ah1, bal, aA1, 0, 0, 0);
        aB0 = __builtin_amdgcn_mfma_f32_32x32x16_bf16(ah0, bbl, aB0, 0, 0, 0);
        aB1 = __builtin_amdgcn_mfma_f32_32x32x16_bf16(ah1, bbl, aB1, 0, 0, 0);
        aA0 = __builtin_amdgcn_mfma_f32_32x32x16_bf16(al0, bah, aA0, 0, 0, 0);
        aA1 = __builtin_amdgcn_mfma_f32_32x32x16_bf16(al1, bah, aA1, 0, 0, 0);
        aB0 = __builtin_amdgcn_mfma_f32_32x32x16_bf16(al0, bbh, aB0, 0, 0, 0);
        aB1 = __builtin_amdgcn_mfma_f32_32x32x16_bf16(al1, bbh, aB1, 0, 0, 0);
    }

    float bcol = b1[colw];
    #pragma unroll
    for (int reg = 0; reg < 16; ++reg) {
        int rr = (reg & 3) + ((reg >> 2) << 3) + (khalf << 2);
        size_t r0o = (size_t)(row0 + rr) * 256;
        size_t r1o = (size_t)(row0 + rr + 32) * 256;
        P[r0o + colw]       = aA0[reg] + bcol;
        P[r1o + colw]       = aA1[reg] + bcol;
        P[r0o + 128 + colw] = aB0[reg];
        P[r1o + 128 + colw] = aB1[reg];
        hbw[r0o + 128 + colw] = 0.0f;
        hbw[r1o + 128 + colw] = 0.0f;
    }
}

// ---------------- chained 2-stage MFMA GEMM (layer-3 node MLP) ------------
__global__ __launch_bounds__(256) void mfma_chain2_kernel(
    const float* __restrict__ A1, int lda1, int KA1,
    const float* __restrict__ A2, int lda2, int KA,
    const unsigned short* __restrict__ w1hi, const unsigned short* __restrict__ w1lo,
    const float* __restrict__ bias1, int flags1,
    const unsigned short* __restrict__ w2hi, const unsigned short* __restrict__ w2lo,
    const float* __restrict__ bias2, int flags2,
    float* __restrict__ out, int ldout)
{
    __shared__ char a_hi[16384];
    __shared__ char a_lo[16384];

    const int tid   = threadIdx.x;
    const int lane  = tid & 63;
    const int w     = tid >> 6;
    const int row0  = blockIdx.x * 64;
    const int lid   = lane & 31;
    const int khalf = lane >> 5;
    const int colw  = (w << 5) + lid;
    const int K16   = (KA + 15) & ~15;

    f32x16 acc0, acc1;
    #pragma unroll
    for (int i = 0; i < 16; ++i) { acc0[i] = 0.f; acc1[i] = 0.f; }

    for (int kc = 0; kc < K16; kc += 128) {
        int CK = K16 - kc; if (CK > 128) CK = 128;
        __syncthreads();
        stage_a_chunk(a_hi, a_lo, A1, lda1, KA1, A2, lda2, KA, kc, row0, lane, w);
        __syncthreads();
        mfma_chunk(a_hi, a_lo, w1hi, w1lo, kc, CK >> 4, lid, khalf, colw, acc0, acc1);
    }

    __syncthreads();
    {
        float b1c = (flags1 & FLAG_BIAS) ? bias1[colw] : 0.0f;
        #pragma unroll
        for (int reg = 0; reg < 16; ++reg) {
            int rr = (reg & 3) + ((reg >> 2) << 3) + (khalf << 2);
            float v0 = acc0[reg] + b1c;
            float v1 = acc1[reg] + b1c;
            if (flags1 & FLAG_SILU) { v0 = silu_f(v0); v1 = silu_f(v1); }
            store_split(a_hi, a_lo, rr, colw, v0);
            store_split(a_hi, a_lo, rr + 32, colw, v1);
        }
    }
    __syncthreads();

    #pragma unroll
    for (int i = 0; i < 16; ++i) { acc0[i] = 0.f; acc1[i] = 0.f; }
    mfma_chunk(a_hi, a_lo, w2hi, w2lo, 0, 8, lid, khalf, colw, acc0, acc1);

    float bcol = (flags2 & FLAG_BIAS) ? bias2[colw] : 0.0f;
    #pragma unroll
    for (int reg = 0; reg < 16; ++reg) {
        int rr = (reg & 3) + ((reg >> 2) << 3) + (khalf << 2);
        float v0 = acc0[reg] + bcol;
        float v1 = acc1[reg] + bcol;
        float* p0 = &out[(size_t)(row0 + rr) * ldout + colw];
        float* p1 = &out[(size_t)(row0 + rr + 32) * ldout + colw];
        if (flags2 & FLAG_ACC) { v0 += *p0; v1 += *p1; }
        if (flags2 & FLAG_SILU) { v0 = silu_f(v0); v1 = silu_f(v1); }
        *p0 = v0; *p1 = v1;
    }
}

// ---------------- chain3: node MLP (l) + projection (l+1) + agg zero ------
__global__ __launch_bounds__(256) void chain3_node_kernel(
    const float* __restrict__ hb, const float* __restrict__ h0,
    const unsigned short* __restrict__ w1hi, const unsigned short* __restrict__ w1lo,
    const float* __restrict__ nb1v,
    const unsigned short* __restrict__ w2hi, const unsigned short* __restrict__ w2lo,
    const float* __restrict__ nb2v,
    const unsigned short* __restrict__ pahi, const unsigned short* __restrict__ palo,
    const unsigned short* __restrict__ pbhi, const unsigned short* __restrict__ pblo,
    const float* __restrict__ b1n,
    float* __restrict__ hbw, float* __restrict__ P)
{
    __shared__ char a_hi[16384];
    __shared__ char a_lo[16384];

    const int tid   = threadIdx.x;
    const int lane  = tid & 63;
    const int w     = tid >> 6;
    const int row0  = blockIdx.x * 64;
    const int lid   = lane & 31;
    const int khalf = lane >> 5;
    const int colw  = (w << 5) + lid;

    // stage 1: silu([hb|h0]@nw1 + nb1), K=271
    f32x16 acc0, acc1;
    #pragma unroll
    for (int i = 0; i < 16; ++i) { acc0[i] = 0.f; acc1[i] = 0.f; }
    for (int kc = 0; kc < 272; kc += 128) {
        int CK = 272 - kc; if (CK > 128) CK = 128;
        __syncthreads();
        stage_a_chunk(a_hi, a_lo, hb, 256, 256, h0, F_IN, 271, kc, row0, lane, w);
        __syncthreads();
        mfma_chunk(a_hi, a_lo, w1hi, w1lo, kc, CK >> 4, lid, khalf, colw, acc0, acc1);
    }
    __syncthreads();
    {
        float b1c = nb1v[colw];
        #pragma unroll
        for (int reg = 0; reg < 16; ++reg) {
            int rr = (reg & 3) + ((reg >> 2) << 3) + (khalf << 2);
            store_split(a_hi, a_lo, rr, colw, silu_f(acc0[reg] + b1c));
            store_split(a_hi, a_lo, rr + 32, colw, silu_f(acc1[reg] + b1c));
        }
    }
    __syncthreads();

    // stage 2: h' = h + (t1@nw2 + nb2); write h'; zero agg; split h' into LDS
    #pragma unroll
    for (int i = 0; i < 16; ++i) { acc0[i] = 0.f; acc1[i] = 0.f; }
    mfma_chunk(a_hi, a_lo, w2hi, w2lo, 0, 8, lid, khalf, colw, acc0, acc1);
    __syncthreads();
    {
        float b2c = nb2v[colw];
        #pragma unroll
        for (int reg = 0; reg < 16; ++reg) {
            int rr = (reg & 3) + ((reg >> 2) << 3) + (khalf << 2);
            size_t r0o = (size_t)(row0 + rr) * 256;
            size_t r1o = (size_t)(row0 + rr + 32) * 256;
            float v0 = acc0[reg] + b2c + hbw[r0o + colw];
            float v1 = acc1[reg] + b2c + hbw[r1o + colw];
            hbw[r0o + colw] = v0;
            hbw[r1o + colw] = v1;
            hbw[r0o + 128 + colw] = 0.0f;
            hbw[r1o + 128 + colw] = 0.0f;
            store_split(a_hi, a_lo, rr, colw, v0);
            store_split(a_hi, a_lo, rr + 32, colw, v1);
        }
    }
    __syncthreads();

    // stage 3: projection for next layer
    f32x16 aA0, aA1, aB0, aB1;
    #pragma unroll
    for (int i = 0; i < 16; ++i) { aA0[i]=0.f; aA1[i]=0.f; aB0[i]=0.f; aB1[i]=0.f; }
    const int sw0 = (lid & 7) << 4;
    #pragma unroll 2
    for (int ks = 0; ks < 8; ++ks) {
        int ab = (lid * 256 + ks * 32 + khalf * 16) ^ sw0;
        bf16x8 ah0 = *(const bf16x8*)(a_hi + ab);
        bf16x8 al0 = *(const bf16x8*)(a_lo + ab);
        bf16x8 ah1 = *(const bf16x8*)(a_hi + ab + 8192);
        bf16x8 al1 = *(const bf16x8*)(a_lo + ab + 8192);
        int slot = (ks << 1) + khalf;
        bf16x8 bah = *(const bf16x8*)(pahi + (slot << 10) + (colw << 3));
        bf16x8 bal = *(const bf16x8*)(palo + (slot << 10) + (colw << 3));
        bf16x8 bbh = *(const bf16x8*)(pbhi + (slot << 10) + (colw << 3));
        bf16x8 bbl = *(const bf16x8*)(pblo + (slot << 10) + (colw << 3));
        aA0 = __builtin_amdgcn_mfma_f32_32x32x16_bf16(ah0, bah, aA0, 0, 0, 0);
        aA1 = __builtin_amdgcn_mfma_f32_32x32x16_bf16(ah1, bah, aA1, 0, 0, 0);
        aB0 = __builtin_amdgcn_mfma_f32_32x32x16_bf16(ah0, bbh, aB0, 0, 0, 0);
        aB1 = __builtin_amdgcn_mfma_f32_32x32x16_bf16(ah1, bbh, aB1, 0, 0, 0);
        aA0 = __builtin_amdgcn_mfma_f32_32x32x16_bf16(ah0, bal, aA0, 0, 0, 0);
        aA1 = __builtin_amdgcn_mfma_f32_32x32x16_bf16(ah1, bal, aA1, 0, 0, 0);
        aB0 = __builtin_amdgcn_mfma_f32_32x32x16_bf16(ah0, bbl, aB0, 0, 0, 0);
        aB1 = __builtin_amdgcn_mfma_f32_32x32x16_bf16(ah1, bbl, aB1, 0, 0, 0);
        aA0 = __builtin_amdgcn_mfma_f32_32x32x16_bf16(al0, bah, aA0, 0, 0, 0);
        aA1 = __builtin_amdgcn_mfma_f32_32x32x16_bf16(al1, bah, aA1, 0, 0, 0);
        aB0 = __builtin_amdgcn_mfma_f32_32x32x16_bf16(al0, bbh, aB0, 0, 0, 0);
        aB1 = __builtin_amdgcn_mfma_f32_32x32x16_bf16(al1, bbh, aB1, 0, 0, 0);
    }
    float bcol = b1n[colw];
    #pragma unroll
    for (int reg = 0; reg < 16; ++reg) {
        int rr = (reg & 3) + ((reg >> 2) << 3) + (khalf << 2);
        size_t r0o = (size_t)(row0 + rr) * 256;
        size_t r1o = (size_t)(row0 + rr + 32) * 256;
        P[r0o + colw]       = aA0[reg] + bcol;
        P[r1o + colw]       = aA1[reg] + bcol;
        P[r0o + 128 + colw] = aB0[reg];
        P[r1o + 128 + colw] = aB1[reg];
    }
}

// ---------------- chain3 decoder: dw1 -> dw2 -> gw1 -----------------------
__global__ __launch_bounds__(256) void chain3_dec_kernel(
    const float* __restrict__ hb,
    const unsigned short* __restrict__ w1hi, const unsigned short* __restrict__ w1lo,
    const float* __restrict__ b1,
    const unsigned short* __restrict__ w2hi, const unsigned short* __restrict__ w2lo,
    const float* __restrict__ b2,
    const unsigned short* __restrict__ w3hi, const unsigned short* __restrict__ w3lo,
    const float* __restrict__ b3,
    float* __restrict__ out)
{
    __shared__ char a_hi[16384];
    __shared__ char a_lo[16384];

    const int tid   = threadIdx.x;
    const int lane  = tid & 63;
    const int w     = tid >> 6;
    const int row0  = blockIdx.x * 64;
    const int lid   = lane & 31;
    const int khalf = lane >> 5;
    const int colw  = (w << 5) + lid;

    f32x16 acc0, acc1;

    #pragma unroll
    for (int i = 0; i < 16; ++i) { acc0[i] = 0.f; acc1[i] = 0.f; }
    stage_a_chunk(a_hi, a_lo, hb, 256, 128, nullptr, 0, 128, 0, row0, lane, w);
    __syncthreads();
    mfma_chunk(a_hi, a_lo, w1hi, w1lo, 0, 8, lid, khalf, colw, acc0, acc1);
    __syncthreads();
    {
        float bc = b1[colw];
        #pragma unroll
        for (int reg = 0; reg < 16; ++reg) {
            int rr = (reg & 3) + ((reg >> 2) << 3) + (khalf << 2);
            store_split(a_hi, a_lo, rr, colw, silu_f(acc0[reg] + bc));
            store_split(a_hi, a_lo, rr + 32, colw, silu_f(acc1[reg] + bc));
        }
    }
    __syncthreads();

    #pragma unroll
    for (int i = 0; i < 16; ++i) { acc0[i] = 0.f; acc1[i] = 0.f; }
    mfma_chunk(a_hi, a_lo, w2hi, w2lo, 0, 8, lid, khalf, colw, acc0, acc1);
    __syncthreads();
    {
        float bc = b2[colw];
        #pragma unroll
        for (int reg = 0; reg < 16; ++reg) {
            int rr = (reg & 3) + ((reg >> 2) << 3) + (khalf << 2);
            store_split(a_hi, a_lo, rr, colw, acc0[reg] + bc);
            store_split(a_hi, a_lo, rr + 32, colw, acc1[reg] + bc);
        }
    }
    __syncthreads();

    #pragma unroll
    for (int i = 0; i < 16; ++i) { acc0[i] = 0.f; acc1[i] = 0.f; }
    mfma_chunk(a_hi, a_lo, w3hi, w3lo, 0, 8, lid, khalf, colw, acc0, acc1);
    float bc = b3[colw];
    #pragma unroll
    for (int reg = 0; reg < 16; ++reg) {
        int rr = (reg & 3) + ((reg >> 2) << 3) + (khalf << 2);
        out[(size_t)(row0 + rr) * HID + colw]      = silu_f(acc0[reg] + bc);
        out[(size_t)(row0 + rr + 32) * HID + colw] = silu_f(acc1[reg] + bc);
    }
}

// ---------------- fused edge kernel: 32 row-sorted edges (high occupancy) --
__global__ __launch_bounds__(256) void edge_kernel(
    const float* __restrict__ P,
    const int* __restrict__ srow, const int* __restrict__ scol,
    const float* __restrict__ srad, const float* __restrict__ sea,
    const unsigned short* __restrict__ w2tb_hi,
    const unsigned short* __restrict__ w2tb_lo,
    const float* __restrict__ b2,
    const float* __restrict__ wr, const float* __restrict__ we,
    float* __restrict__ hb)
{
    // union: phase1/2 = a_hi[32][128]bf16 (8KB) + a_lo (8KB); phase2b/3 = f32 [32][132]
    __shared__ char smem[17408];
    __shared__ int   s_row[32];
    __shared__ int   s_col[32];
    __shared__ float s_rad[32];
    __shared__ float s_ea4[32 * 4];
    __shared__ int   s_segstart[34];
    __shared__ int   s_nseg;

    char* a_hi = smem;
    char* a_lo = smem + 8192;
    float* s_ef = (float*)smem;

    const int tid  = threadIdx.x;
    const int lane = tid & 63;
    const int w    = tid >> 6;
    const int p0   = blockIdx.x * 32;

    if (tid < 32) {
        s_row[tid] = srow[p0 + tid];
        s_col[tid] = scol[p0 + tid];
        s_rad[tid] = srad[p0 + tid];
        *(float4*)&s_ea4[tid * 4] = *(const float4*)&sea[(size_t)(p0 + tid) * 4];
    }
    __syncthreads();

    if (tid < 32) {
        bool flag = (tid == 0) || (s_row[tid] != s_row[tid - 1]);
        unsigned long long mask = __ballot(flag);
        int idx = __popcll(mask & ((1ull << tid) - 1));
        if (flag) s_segstart[idx] = tid;
        if (tid == 0) { int ns = __popcll(mask); s_nseg = ns; s_segstart[ns] = 32; }
    }

    // phase 1: pre1 -> silu -> split bf16 -> LDS (vec2 packed math)
    const int k2 = lane * 2;
    const vf2 wrv = *(const vf2*)&wr[k2];
    const vf2 wa0 = *(const vf2*)&we[0 * 128 + k2];
    const vf2 wa1 = *(const vf2*)&we[1 * 128 + k2];
    const vf2 wa2 = *(const vf2*)&we[2 * 128 + k2];
    const vf2 wa3 = *(const vf2*)&we[3 * 128 + k2];
    #pragma unroll
    for (int it = 0; it < 8; ++it) {
        int et = it * 4 + w;
        int r = s_row[et], c = s_col[et];
        float rad = s_rad[et];
        float4 ea = *(const float4*)&s_ea4[et * 4];
        vf2 ps = *(const vf2*)&P[(size_t)r * 256 + k2];
        vf2 pt = *(const vf2*)&P[(size_t)c * 256 + 128 + k2];
        vf2 pre = ps + pt;
        pre += rad * wrv;
        pre += ea.x * wa0;
        pre += ea.y * wa1;
        pre += ea.z * wa2;
        pre += ea.w * wa3;
        vf2 sl;
        sl.x = silu_f(pre.x);
        sl.y = silu_f(pre.y);
        unsigned hi2, lo2;
        split2v(sl, hi2, lo2);
        int byte = (et * 256 + lane * 4) ^ ((et & 7) << 4);
        *(unsigned*)(a_hi + byte) = hi2;
        *(unsigned*)(a_lo + byte) = lo2;
    }
    __syncthreads();

    // phase 2: [32x128] @ [128x128] split-bf16 MFMA (B streamed via L1)
    const int lid   = lane & 31;
    const int khalf = lane >> 5;
    const int colw  = (w << 5) + lid;
    f32x16 acc0;
    #pragma unroll
    for (int i = 0; i < 16; ++i) acc0[i] = 0.f;
    {
        const int sw0 = (lid & 7) << 4;
        #pragma unroll 2
        for (int ks = 0; ks < 8; ++ks) {
            int ab = (lid * 256 + ks * 32 + khalf * 16) ^ sw0;
            bf16x8 ah = *(const bf16x8*)(a_hi + ab);
            bf16x8 al = *(const bf16x8*)(a_lo + ab);
            int slot = (ks << 1) + khalf;
            bf16x8 bh = *(const bf16x8*)(w2tb_hi + (slot << 10) + (colw << 3));
            bf16x8 bl = *(const bf16x8*)(w2tb_lo + (slot << 10) + (colw << 3));
            acc0 = __builtin_amdgcn_mfma_f32_32x32x16_bf16(ah, bh, acc0, 0, 0, 0);
            acc0 = __builtin_amdgcn_mfma_f32_32x32x16_bf16(ah, bl, acc0, 0, 0, 0);
            acc0 = __builtin_amdgcn_mfma_f32_32x32x16_bf16(al, bh, acc0, 0, 0, 0);
        }
    }
    __syncthreads();

    // phase 2b: silu(acc + b2) -> s_ef (f32, 132-stride)
    float bcol = b2[colw];
    #pragma unroll
    for (int reg = 0; reg < 16; ++reg) {
        int rr = (reg & 3) + ((reg >> 2) << 3) + (khalf << 2);
        s_ef[rr * 132 + colw] = silu_f(acc0[reg] + bcol);
    }
    __syncthreads();

    // phase 3: segmented reduce; interior rows -> store, boundary -> atomics
    const int jg = tid & 31, rg = tid >> 5;
    const int j = jg * 4;
    const int nseg = s_nseg;
    for (int s = rg; s < nseg; s += 8) {
        int sp0 = s_segstart[s], sp1 = s_segstart[s + 1];
        float v0 = 0.f, v1 = 0.f, v2 = 0.f, v3 = 0.f;
        for (int p = sp0; p < sp1; ++p) {
            float4 q = *(const float4*)&s_ef[p * 132 + j];
            v0 += q.x; v1 += q.y; v2 += q.z; v3 += q.w;
        }
        int rowId = s_row[sp0];
        bool interior = true;
        if (sp0 == 0 && p0 > 0 && srow[p0 - 1] == rowId) interior = false;
        if (sp1 == 32 && p0 + 32 < N_EDGES && srow[p0 + 32] == rowId) interior = false;
        float* dst = &hb[(size_t)rowId * 256 + 128 + j];
        if (interior) {
            *(float4*)dst = make_float4(v0, v1, v2, v3);
        } else {
            atomicAdd(&dst[0], v0); atomicAdd(&dst[1], v1);
            atomicAdd(&dst[2], v2); atomicAdd(&dst[3], v3);
        }
    }
}

extern "C" void kernel_launch(void* const* d_in, const int* in_sizes, int n_in,
                              void* d_out, int out_size, void* d_ws, size_t ws_size,
                              hipStream_t stream)
{
    const float* h0       = (const float*)d_in[0];
    const float* x        = (const float*)d_in[1];
    const int*   edges    = (const int*)  d_in[2];
    const float* edge_attr= (const float*)d_in[3];
    const float* emb_w    = (const float*)d_in[4];
    const float* emb_b    = (const float*)d_in[5];
    const float* ew1      = (const float*)d_in[6];
    const float* eb1      = (const float*)d_in[7];
    const float* ew2      = (const float*)d_in[8];
    const float* eb2      = (const float*)d_in[9];
    const float* nw1      = (const float*)d_in[10];
    const float* nb1      = (const float*)d_in[11];
    const float* nw2      = (const float*)d_in[12];
    const float* nb2      = (const float*)d_in[13];
    const float* dw1      = (const float*)d_in[14];
    const float* db1      = (const float*)d_in[15];
    const float* dw2      = (const float*)d_in[16];
    const float* db2      = (const float*)d_in[17];
    const float* gw1      = (const float*)d_in[18];
    const float* gb1      = (const float*)d_in[19];
    const float* gw2      = (const float*)d_in[20];
    const float* gb2      = (const float*)d_in[21];
    float* out = (float*)d_out;

    char* ws = (char*)d_ws;
    const size_t SZ_HB = (size_t)N_NODES * 256 * 4;
    const size_t SZ_T  = (size_t)N_NODES * HID * 4;
    const size_t SZ_E  = (size_t)N_EDGES * 4;
    float* hb     = (float*)(ws);                       // [N,256] = [h | agg]
    float* P      = (float*)(ws + SZ_HB);               // [N,256]
    float* tmp1   = (float*)(ws + SZ_HB * 2);           // [N,128]
    char*  base   = ws + SZ_HB * 2 + SZ_T;
    float* radial = (float*)(base);                     // dead after scatter
    int*   s_row  = (int*)  (base + SZ_E);
    int*   s_col  = (int*)  (base + SZ_E * 2);
    float* s_rad  = (float*)(base + SZ_E * 3);
    float* s_ea   = (float*)(base + SZ_E * 4);
    int*   rowptr = (int*)  (base + SZ_E * 8);
    int*   cnt    = (int*)  (base + SZ_E * 8 + (N_NODES + 64) * 4);
    unsigned short* w_hi = (unsigned short*)radial;
    unsigned short* w_lo = w_hi + W_TOTAL;

    const int* erow = edges;
    const int* ecol = edges + N_EDGES;

    radial_kernel<<<N_EDGES / 256, 256, 0, stream>>>(x, erow, ecol, radial);

    hipMemsetAsync(cnt, 0, N_NODES * 4, stream);
    hist_kernel<<<N_EDGES / 256, 256, 0, stream>>>(erow, cnt);
    scan_kernel<<<1, 1024, 0, stream>>>(cnt, rowptr);
    hipMemsetAsync(cnt, 0, N_NODES * 4, stream);
    scatter_kernel<<<N_EDGES / 256, 256, 0, stream>>>(
        erow, ecol, radial, edge_attr, rowptr, cnt, s_row, s_col, s_rad, s_ea);

    prep_all_kernel<<<dim3(136, 23), 256, 0, stream>>>(
        ew1, ew2, nw1, nw2, dw1, dw2, gw1, w_hi, w_lo);

    gemm_kernel<<<(N_NODES + 31) / 32, 256, 0, stream>>>(
        h0, F_IN, emb_w, HID, emb_b, hb, 256, N_NODES, F_IN, HID, FLAG_BIAS);

    // layer-0 projection (+agg zero)
    mfma_proj_kernel<<<625, 256, 0, stream>>>(
        hb, w_hi + OFF_W1A, w_lo + OFF_W1A, w_hi + OFF_W1B, w_lo + OFF_W1B,
        eb1, P, hb);

    for (int l = 0; l < NLAYERS; ++l) {
        const float* W1   = ew1 + (size_t)l * 261 * 128;
        const float* b2v  = eb2 + l * 128;
        const float* nb1v = nb1 + l * 128;
        const float* nb2v = nb2 + l * 128;

        edge_kernel<<<N_EDGES / 32, 256, 0, stream>>>(
            P, s_row, s_col, s_rad, s_ea,
            w_hi + OFF_W2 + (size_t)l * 16384, w_lo + OFF_W2 + (size_t)l * 16384,
            b2v, W1 + 256 * 128, W1 + 257 * 128, hb);

        if (l < NLAYERS - 1) {
            chain3_node_kernel<<<625, 256, 0, stream>>>(
                hb, h0,
                w_hi + OFF_NW1 + l * 34816, w_lo + OFF_NW1 + l * 34816, nb1v,
                w_hi + OFF_NW2 + l * 16384, w_lo + OFF_NW2 + l * 16384, nb2v,
                w_hi + OFF_W1A + (l + 1) * 16384, w_lo + OFF_W1A + (l + 1) * 16384,
                w_hi + OFF_W1B + (l + 1) * 16384, w_lo + OFF_W1B + (l + 1) * 16384,
                eb1 + (l + 1) * 128,
                hb, P);
        } else {
            mfma_chain2_kernel<<<625, 256, 0, stream>>>(
                hb, 256, 256, h0, F_IN, 271,
                w_hi + OFF_NW1 + l * 34816, w_lo + OFF_NW1 + l * 34816,
                nb1v, FLAG_BIAS | FLAG_SILU,
                w_hi + OFF_NW2 + l * 16384, w_lo + OFF_NW2 + l * 16384,
                nb2v, FLAG_BIAS | FLAG_ACC,
                hb, 256);
        }
    }

    // decoder
    chain3_dec_kernel<<<625, 256, 0, stream>>>(
        hb,
        w_hi + OFF_DW1, w_lo + OFF_DW1, db1,
        w_hi + OFF_DW2, w_lo + OFF_DW2, db2,
        w_hi + OFF_GW1, w_lo + OFF_GW1, gb1,
        tmp1);
    gemm_kernel<<<(N_NODES + 31) / 32, 256, 0, stream>>>(
        tmp1, HID, gw2, NOUT, gb2, out, NOUT, N_NODES, HID, NOUT, FLAG_BIAS);
}

// Round 14
// 836.898 us; speedup vs baseline: 1.1723x; 1.1723x over previous
//
#include <hip/hip_runtime.h>
#include <hip/hip_bf16.h>
#include <math.h>

#define N_NODES 40000
#define N_EDGES 640000
#define F_IN    15
#define HID     128
#define NLAYERS 4
#define NOUT    21

#define FLAG_BIAS 1
#define FLAG_ACC  2
#define FLAG_SILU 4

typedef __attribute__((ext_vector_type(8))) short bf16x8;
typedef __attribute__((ext_vector_type(16))) float f32x16;
typedef __attribute__((ext_vector_type(2)))  float vf2;

__device__ __forceinline__ float silu_f(float x) {
    return x * __builtin_amdgcn_rcpf(1.0f + __expf(-x));
}

__device__ __forceinline__ unsigned short f2bf(float f) {
    unsigned u = __builtin_bit_cast(unsigned, f);
    unsigned r = (u + 0x7FFFu + ((u >> 16) & 1u)) >> 16;
    return (unsigned short)r;
}
__device__ __forceinline__ float bf2f(unsigned short b) {
    return __builtin_bit_cast(float, (unsigned)b << 16);
}

__device__ __forceinline__ void split2v(vf2 v, unsigned& hi2, unsigned& lo2) {
    union { __hip_bfloat162 b; unsigned u; } ch, cl;
    ch.b = __float22bfloat162_rn(make_float2(v.x, v.y));
    vf2 h;
    h.x = __builtin_bit_cast(float, ch.u << 16);
    h.y = __builtin_bit_cast(float, ch.u & 0xFFFF0000u);
    vf2 r = v - h;
    cl.b = __float22bfloat162_rn(make_float2(r.x, r.y));
    hi2 = ch.u;
    lo2 = cl.u;
}

__device__ __forceinline__ void store_split(char* a_hi, char* a_lo, int row, int col, float v) {
    unsigned short h = f2bf(v);
    unsigned short l = f2bf(v - bf2f(h));
    int byte = (row * 256 + col * 2) ^ ((row & 7) << 4);
    *(unsigned short*)(a_hi + byte) = h;
    *(unsigned short*)(a_lo + byte) = l;
}

// ---------------- radial ----------------
__global__ __launch_bounds__(256) void radial_kernel(
    const float* __restrict__ x, const int* __restrict__ erow,
    const int* __restrict__ ecol, float* __restrict__ radial)
{
    int e = blockIdx.x * 256 + threadIdx.x;
    if (e >= N_EDGES) return;
    int r = erow[e], c = ecol[e];
    float dx = x[r*3+0] - x[c*3+0];
    float dy = x[r*3+1] - x[c*3+1];
    float dz = x[r*3+2] - x[c*3+2];
    radial[e] = dx*dx + dy*dy + dz*dz;
}

// ---------------- CSR build ----------------
__global__ __launch_bounds__(256) void hist_kernel(
    const int* __restrict__ erow, int* __restrict__ cnt)
{
    int e = blockIdx.x * 256 + threadIdx.x;
    if (e < N_EDGES) atomicAdd(&cnt[erow[e]], 1);
}

__global__ __launch_bounds__(1024) void scan_kernel(
    const int* __restrict__ cnt, int* __restrict__ rowptr)
{
    __shared__ int s[1024];
    __shared__ int carry_s;
    const int tid = threadIdx.x;
    if (tid == 0) { carry_s = 0; rowptr[0] = 0; }
    __syncthreads();
    for (int base = 0; base < N_NODES; base += 1024) {
        int i = base + tid;
        int v = (i < N_NODES) ? cnt[i] : 0;
        s[tid] = v;
        __syncthreads();
        for (int off = 1; off < 1024; off <<= 1) {
            int t = (tid >= off) ? s[tid - off] : 0;
            __syncthreads();
            s[tid] += t;
            __syncthreads();
        }
        int c = carry_s;
        if (i < N_NODES) rowptr[i + 1] = c + s[tid];
        __syncthreads();
        if (tid == 1023) carry_s = c + s[1023];
        __syncthreads();
    }
}

__global__ __launch_bounds__(256) void scatter_kernel(
    const int* __restrict__ erow, const int* __restrict__ ecol,
    const float* __restrict__ radial, const float* __restrict__ edge_attr,
    const int* __restrict__ rowptr, int* __restrict__ fill,
    int* __restrict__ srow, int* __restrict__ scol,
    float* __restrict__ srad, float* __restrict__ sea)
{
    int e = blockIdx.x * 256 + threadIdx.x;
    if (e >= N_EDGES) return;
    int r = erow[e];
    int pos = rowptr[r] + atomicAdd(&fill[r], 1);
    srow[pos] = r;
    scol[pos] = ecol[e];
    srad[pos] = radial[e];
    float4 ea = *(const float4*)&edge_attr[(size_t)e * 4];
    *(float4*)&sea[(size_t)pos * 4] = ea;
}

// ---------------- unified weight split/transpose prep ----------------
#define OFF_W2   0
#define OFF_W1A  65536
#define OFF_W1B  131072
#define OFF_NW1  196608
#define OFF_NW2  335872
#define OFF_DW1  401408
#define OFF_DW2  417792
#define OFF_GW1  434176
#define OFF_EMB  450560
#define OFF_GW2  452608
#define W_TOTAL  468992

__global__ __launch_bounds__(256) void prep_all_kernel(
    const float* __restrict__ ew1, const float* __restrict__ ew2,
    const float* __restrict__ nw1, const float* __restrict__ nw2,
    const float* __restrict__ dw1, const float* __restrict__ dw2,
    const float* __restrict__ gw1, const float* __restrict__ emb_w,
    const float* __restrict__ gw2,
    unsigned short* __restrict__ hi, unsigned short* __restrict__ lo)
{
    const int T = blockIdx.y;
    int srcSel, srcOff, K, dstOff;
    if (T < 4)       { srcSel=1; srcOff=T*16384;           K=128; dstOff=OFF_W2 +T*16384; }
    else if (T < 8)  { int l=T-4;  srcSel=0; srcOff=l*33408;        K=128; dstOff=OFF_W1A+l*16384; }
    else if (T < 12) { int l=T-8;  srcSel=0; srcOff=l*33408+16384;  K=128; dstOff=OFF_W1B+l*16384; }
    else if (T < 16) { int l=T-12; srcSel=2; srcOff=l*34688;        K=271; dstOff=OFF_NW1+l*34816; }
    else if (T < 20) { int l=T-16; srcSel=3; srcOff=l*16384;        K=128; dstOff=OFF_NW2+l*16384; }
    else if (T == 20){ srcSel=4; srcOff=0; K=128; dstOff=OFF_DW1; }
    else if (T == 21){ srcSel=5; srcOff=0; K=128; dstOff=OFF_DW2; }
    else if (T == 22){ srcSel=6; srcOff=0; K=128; dstOff=OFF_GW1; }
    else if (T == 23){ srcSel=7; srcOff=0; K=15;  dstOff=OFF_EMB; }
    else             { srcSel=8; srcOff=0; K=128; dstOff=OFF_GW2; }

    const float* src;
    switch (srcSel) {
        case 0: src = ew1; break;  case 1: src = ew2; break;
        case 2: src = nw1; break;  case 3: src = nw2; break;
        case 4: src = dw1; break;  case 5: src = dw2; break;
        case 6: src = gw1; break;  case 7: src = emb_w; break;
        default: src = gw2; break;
    }
    int K16 = (K + 15) & ~15;
    int idx = blockIdx.x * 256 + threadIdx.x;
    if (idx >= K16 * 128) return;
    int k = idx >> 7, c = idx & 127;
    float v = 0.0f;
    if (k < K) {
        if (srcSel == 8) { if (c < NOUT) v = src[k * NOUT + c]; }
        else v = src[srcOff + k * 128 + c];
    }
    unsigned short h = f2bf(v);
    unsigned short lw = f2bf(v - bf2f(h));
    int o = dstOff + ((k >> 3) << 10) + (c << 3) + (k & 7);
    hi[o] = h; lo[o] = lw;
}

// ---------------- shared MFMA helpers ----------------
__device__ __forceinline__ void stage_a_chunk(
    char* a_hi, char* a_lo,
    const float* __restrict__ A1, int lda1, int KA1,
    const float* __restrict__ A2, int lda2, int KA,
    int kc, int row0, int lane, int w)
{
    if (kc + 128 <= KA1) {
        #pragma unroll 4
        for (int it = 0; it < 16; ++it) {
            int row = it * 4 + w;
            vf2 v = *(const vf2*)&A1[(size_t)(row0 + row) * lda1 + kc + lane * 2];
            unsigned hi2, lo2;
            split2v(v, hi2, lo2);
            int byte = (row * 256 + lane * 4) ^ ((row & 7) << 4);
            *(unsigned*)(a_hi + byte) = hi2;
            *(unsigned*)(a_lo + byte) = lo2;
        }
    } else {
        for (int it = 0; it < 16; ++it) {
            int row = it * 4 + w;
            vf2 vv;
            #pragma unroll
            for (int d = 0; d < 2; ++d) {
                int k = kc + lane * 2 + d;
                float v = 0.0f;
                if (k < KA1) v = A1[(size_t)(row0 + row) * lda1 + k];
                else if (k < KA) v = A2[(size_t)(row0 + row) * lda2 + (k - KA1)];
                vv[d] = v;
            }
            unsigned hi2, lo2;
            split2v(vv, hi2, lo2);
            int byte = (row * 256 + lane * 4) ^ ((row & 7) << 4);
            *(unsigned*)(a_hi + byte) = hi2;
            *(unsigned*)(a_lo + byte) = lo2;
        }
    }
}

__device__ __forceinline__ void mfma_chunk(
    const char* a_hi, const char* a_lo,
    const unsigned short* __restrict__ bhi, const unsigned short* __restrict__ blo,
    int kc, int nks, int lid, int khalf, int colw,
    f32x16& acc0, f32x16& acc1)
{
    const int sw0 = (lid & 7) << 4;
    for (int ks = 0; ks < nks; ++ks) {
        int ab = (lid * 256 + ks * 32 + khalf * 16) ^ sw0;
        bf16x8 ah0 = *(const bf16x8*)(a_hi + ab);
        bf16x8 al0 = *(const bf16x8*)(a_lo + ab);
        bf16x8 ah1 = *(const bf16x8*)(a_hi + ab + 8192);
        bf16x8 al1 = *(const bf16x8*)(a_lo + ab + 8192);
        int slot = (kc >> 3) + (ks << 1) + khalf;
        bf16x8 bh = *(const bf16x8*)(bhi + (slot << 10) + (colw << 3));
        bf16x8 bl = *(const bf16x8*)(blo + (slot << 10) + (colw << 3));
        acc0 = __builtin_amdgcn_mfma_f32_32x32x16_bf16(ah0, bh, acc0, 0, 0, 0);
        acc1 = __builtin_amdgcn_mfma_f32_32x32x16_bf16(ah1, bh, acc1, 0, 0, 0);
        acc0 = __builtin_amdgcn_mfma_f32_32x32x16_bf16(ah0, bl, acc0, 0, 0, 0);
        acc1 = __builtin_amdgcn_mfma_f32_32x32x16_bf16(ah1, bl, acc1, 0, 0, 0);
        acc0 = __builtin_amdgcn_mfma_f32_32x32x16_bf16(al0, bh, acc0, 0, 0, 0);
        acc1 = __builtin_amdgcn_mfma_f32_32x32x16_bf16(al1, bh, acc1, 0, 0, 0);
    }
}

// dual-B MFMA over the staged 128-chunk (for projections)
__device__ __forceinline__ void mfma_proj_stage(
    const char* a_hi, const char* a_lo,
    const unsigned short* __restrict__ wahi, const unsigned short* __restrict__ walo,
    const unsigned short* __restrict__ wbhi, const unsigned short* __restrict__ wblo,
    int lid, int khalf, int colw,
    f32x16& aA0, f32x16& aA1, f32x16& aB0, f32x16& aB1)
{
    const int sw0 = (lid & 7) << 4;
    #pragma unroll 2
    for (int ks = 0; ks < 8; ++ks) {
        int ab = (lid * 256 + ks * 32 + khalf * 16) ^ sw0;
        bf16x8 ah0 = *(const bf16x8*)(a_hi + ab);
        bf16x8 al0 = *(const bf16x8*)(a_lo + ab);
        bf16x8 ah1 = *(const bf16x8*)(a_hi + ab + 8192);
        bf16x8 al1 = *(const bf16x8*)(a_lo + ab + 8192);
        int slot = (ks << 1) + khalf;
        bf16x8 bah = *(const bf16x8*)(wahi + (slot << 10) + (colw << 3));
        bf16x8 bal = *(const bf16x8*)(walo + (slot << 10) + (colw << 3));
        bf16x8 bbh = *(const bf16x8*)(wbhi + (slot << 10) + (colw << 3));
        bf16x8 bbl = *(const bf16x8*)(wblo + (slot << 10) + (colw << 3));
        aA0 = __builtin_amdgcn_mfma_f32_32x32x16_bf16(ah0, bah, aA0, 0, 0, 0);
        aA1 = __builtin_amdgcn_mfma_f32_32x32x16_bf16(ah1, bah, aA1, 0, 0, 0);
        aB0 = __builtin_amdgcn_mfma_f32_32x32x16_bf16(ah0, bbh, aB0, 0, 0, 0);
        aB1 = __builtin_amdgcn_mfma_f32_32x32x16_bf16(ah1, bbh, aB1, 0, 0, 0);
        aA0 = __builtin_amdgcn_mfma_f32_32x32x16_bf16(ah0, bal, aA0, 0, 0, 0);
        aA1 = __builtin_amdgcn_mfma_f32_32x32x16_bf16(ah1, bal, aA1, 0, 0, 0);
        aB0 = __builtin_amdgcn_mfma_f32_32x32x16_bf16(ah0, bbl, aB0, 0, 0, 0);
        aB1 = __builtin_amdgcn_mfma_f32_32x32x16_bf16(ah1, bbl, aB1, 0, 0, 0);
        aA0 = __builtin_amdgcn_mfma_f32_32x32x16_bf16(al0, bah, aA0, 0, 0, 0);
        aA1 = __builtin_amdgcn_mfma_f32_32x32x16_bf16(al1, bah, aA1, 0, 0, 0);
        aB0 = __builtin_amdgcn_mfma_f32_32x32x16_bf16(al0, bbh, aB0, 0, 0, 0);
        aB1 = __builtin_amdgcn_mfma_f32_32x32x16_bf16(al1, bbh, aB1, 0, 0, 0);
    }
}

// ---------------- emb + layer-0 projection fused ----------------
// h = h0@emb_w + emb_b (K=15); hb[:,0:128]=h; P = [h@W1a+b1 | h@W1b]; agg=0
__global__ __launch_bounds__(256) void emb_proj_kernel(
    const float* __restrict__ h0,
    const unsigned short* __restrict__ ehi, const unsigned short* __restrict__ elo,
    const float* __restrict__ emb_b,
    const unsigned short* __restrict__ wahi, const unsigned short* __restrict__ walo,
    const unsigned short* __restrict__ wbhi, const unsigned short* __restrict__ wblo,
    const float* __restrict__ b1,
    float* __restrict__ hbw, float* __restrict__ P)
{
    __shared__ char a_hi[16384];
    __shared__ char a_lo[16384];

    const int tid   = threadIdx.x;
    const int lane  = tid & 63;
    const int w     = tid >> 6;
    const int row0  = blockIdx.x * 64;
    const int lid   = lane & 31;
    const int khalf = lane >> 5;
    const int colw  = (w << 5) + lid;

    // stage h0 tile: 64 rows x 16 cols (col 15 zero-padded)
    {
        int row = tid >> 2;
        int c0 = (tid & 3) * 4;
        const float* srcp = &h0[(size_t)(row0 + row) * F_IN];
        vf2 vA, vB;
        vA.x = srcp[c0 + 0];
        vA.y = srcp[c0 + 1];
        vB.x = srcp[c0 + 2];
        vB.y = (c0 + 3 < F_IN) ? srcp[c0 + 3] : 0.0f;
        unsigned h2, l2;
        split2v(vA, h2, l2);
        int byteA = (row * 256 + c0 * 2) ^ ((row & 7) << 4);
        *(unsigned*)(a_hi + byteA) = h2;
        *(unsigned*)(a_lo + byteA) = l2;
        split2v(vB, h2, l2);
        int byteB = (row * 256 + c0 * 2 + 4) ^ ((row & 7) << 4);
        *(unsigned*)(a_hi + byteB) = h2;
        *(unsigned*)(a_lo + byteB) = l2;
    }
    __syncthreads();

    // emb: K=16 (one k16-slice)
    f32x16 acc0, acc1;
    #pragma unroll
    for (int i = 0; i < 16; ++i) { acc0[i] = 0.f; acc1[i] = 0.f; }
    mfma_chunk(a_hi, a_lo, ehi, elo, 0, 1, lid, khalf, colw, acc0, acc1);
    __syncthreads();

    // h -> hb cols 0..127 and split into LDS
    {
        float bc = emb_b[colw];
        #pragma unroll
        for (int reg = 0; reg < 16; ++reg) {
            int rr = (reg & 3) + ((reg >> 2) << 3) + (khalf << 2);
            size_t r0o = (size_t)(row0 + rr) * 256;
            size_t r1o = (size_t)(row0 + rr + 32) * 256;
            float v0 = acc0[reg] + bc;
            float v1 = acc1[reg] + bc;
            hbw[r0o + colw] = v0;
            hbw[r1o + colw] = v1;
            store_split(a_hi, a_lo, rr, colw, v0);
            store_split(a_hi, a_lo, rr + 32, colw, v1);
        }
    }
    __syncthreads();

    // layer-0 projection + agg zero
    f32x16 aA0, aA1, aB0, aB1;
    #pragma unroll
    for (int i = 0; i < 16; ++i) { aA0[i]=0.f; aA1[i]=0.f; aB0[i]=0.f; aB1[i]=0.f; }
    mfma_proj_stage(a_hi, a_lo, wahi, walo, wbhi, wblo, lid, khalf, colw,
                    aA0, aA1, aB0, aB1);

    float bcol = b1[colw];
    #pragma unroll
    for (int reg = 0; reg < 16; ++reg) {
        int rr = (reg & 3) + ((reg >> 2) << 3) + (khalf << 2);
        size_t r0o = (size_t)(row0 + rr) * 256;
        size_t r1o = (size_t)(row0 + rr + 32) * 256;
        P[r0o + colw]       = aA0[reg] + bcol;
        P[r1o + colw]       = aA1[reg] + bcol;
        P[r0o + 128 + colw] = aB0[reg];
        P[r1o + 128 + colw] = aB1[reg];
        hbw[r0o + 128 + colw] = 0.0f;
        hbw[r1o + 128 + colw] = 0.0f;
    }
}

// ---------------- chained 2-stage MFMA GEMM (layer-3 node MLP) ------------
__global__ __launch_bounds__(256) void mfma_chain2_kernel(
    const float* __restrict__ A1, int lda1, int KA1,
    const float* __restrict__ A2, int lda2, int KA,
    const unsigned short* __restrict__ w1hi, const unsigned short* __restrict__ w1lo,
    const float* __restrict__ bias1, int flags1,
    const unsigned short* __restrict__ w2hi, const unsigned short* __restrict__ w2lo,
    const float* __restrict__ bias2, int flags2,
    float* __restrict__ out, int ldout)
{
    __shared__ char a_hi[16384];
    __shared__ char a_lo[16384];

    const int tid   = threadIdx.x;
    const int lane  = tid & 63;
    const int w     = tid >> 6;
    const int row0  = blockIdx.x * 64;
    const int lid   = lane & 31;
    const int khalf = lane >> 5;
    const int colw  = (w << 5) + lid;
    const int K16   = (KA + 15) & ~15;

    f32x16 acc0, acc1;
    #pragma unroll
    for (int i = 0; i < 16; ++i) { acc0[i] = 0.f; acc1[i] = 0.f; }

    for (int kc = 0; kc < K16; kc += 128) {
        int CK = K16 - kc; if (CK > 128) CK = 128;
        __syncthreads();
        stage_a_chunk(a_hi, a_lo, A1, lda1, KA1, A2, lda2, KA, kc, row0, lane, w);
        __syncthreads();
        mfma_chunk(a_hi, a_lo, w1hi, w1lo, kc, CK >> 4, lid, khalf, colw, acc0, acc1);
    }

    __syncthreads();
    {
        float b1c = (flags1 & FLAG_BIAS) ? bias1[colw] : 0.0f;
        #pragma unroll
        for (int reg = 0; reg < 16; ++reg) {
            int rr = (reg & 3) + ((reg >> 2) << 3) + (khalf << 2);
            float v0 = acc0[reg] + b1c;
            float v1 = acc1[reg] + b1c;
            if (flags1 & FLAG_SILU) { v0 = silu_f(v0); v1 = silu_f(v1); }
            store_split(a_hi, a_lo, rr, colw, v0);
            store_split(a_hi, a_lo, rr + 32, colw, v1);
        }
    }
    __syncthreads();

    #pragma unroll
    for (int i = 0; i < 16; ++i) { acc0[i] = 0.f; acc1[i] = 0.f; }
    mfma_chunk(a_hi, a_lo, w2hi, w2lo, 0, 8, lid, khalf, colw, acc0, acc1);

    float bcol = (flags2 & FLAG_BIAS) ? bias2[colw] : 0.0f;
    #pragma unroll
    for (int reg = 0; reg < 16; ++reg) {
        int rr = (reg & 3) + ((reg >> 2) << 3) + (khalf << 2);
        float v0 = acc0[reg] + bcol;
        float v1 = acc1[reg] + bcol;
        float* p0 = &out[(size_t)(row0 + rr) * ldout + colw];
        float* p1 = &out[(size_t)(row0 + rr + 32) * ldout + colw];
        if (flags2 & FLAG_ACC) { v0 += *p0; v1 += *p1; }
        if (flags2 & FLAG_SILU) { v0 = silu_f(v0); v1 = silu_f(v1); }
        *p0 = v0; *p1 = v1;
    }
}

// ---------------- chain3: node MLP (l) + projection (l+1) + agg zero ------
__global__ __launch_bounds__(256) void chain3_node_kernel(
    const float* __restrict__ hb, const float* __restrict__ h0,
    const unsigned short* __restrict__ w1hi, const unsigned short* __restrict__ w1lo,
    const float* __restrict__ nb1v,
    const unsigned short* __restrict__ w2hi, const unsigned short* __restrict__ w2lo,
    const float* __restrict__ nb2v,
    const unsigned short* __restrict__ pahi, const unsigned short* __restrict__ palo,
    const unsigned short* __restrict__ pbhi, const unsigned short* __restrict__ pblo,
    const float* __restrict__ b1n,
    float* __restrict__ hbw, float* __restrict__ P)
{
    __shared__ char a_hi[16384];
    __shared__ char a_lo[16384];

    const int tid   = threadIdx.x;
    const int lane  = tid & 63;
    const int w     = tid >> 6;
    const int row0  = blockIdx.x * 64;
    const int lid   = lane & 31;
    const int khalf = lane >> 5;
    const int colw  = (w << 5) + lid;

    // stage 1: silu([hb|h0]@nw1 + nb1), K=271
    f32x16 acc0, acc1;
    #pragma unroll
    for (int i = 0; i < 16; ++i) { acc0[i] = 0.f; acc1[i] = 0.f; }
    for (int kc = 0; kc < 272; kc += 128) {
        int CK = 272 - kc; if (CK > 128) CK = 128;
        __syncthreads();
        stage_a_chunk(a_hi, a_lo, hb, 256, 256, h0, F_IN, 271, kc, row0, lane, w);
        __syncthreads();
        mfma_chunk(a_hi, a_lo, w1hi, w1lo, kc, CK >> 4, lid, khalf, colw, acc0, acc1);
    }
    __syncthreads();
    {
        float b1c = nb1v[colw];
        #pragma unroll
        for (int reg = 0; reg < 16; ++reg) {
            int rr = (reg & 3) + ((reg >> 2) << 3) + (khalf << 2);
            store_split(a_hi, a_lo, rr, colw, silu_f(acc0[reg] + b1c));
            store_split(a_hi, a_lo, rr + 32, colw, silu_f(acc1[reg] + b1c));
        }
    }
    __syncthreads();

    // stage 2: h' = h + (t1@nw2 + nb2); write h'; zero agg; split h' into LDS
    #pragma unroll
    for (int i = 0; i < 16; ++i) { acc0[i] = 0.f; acc1[i] = 0.f; }
    mfma_chunk(a_hi, a_lo, w2hi, w2lo, 0, 8, lid, khalf, colw, acc0, acc1);
    __syncthreads();
    {
        float b2c = nb2v[colw];
        #pragma unroll
        for (int reg = 0; reg < 16; ++reg) {
            int rr = (reg & 3) + ((reg >> 2) << 3) + (khalf << 2);
            size_t r0o = (size_t)(row0 + rr) * 256;
            size_t r1o = (size_t)(row0 + rr + 32) * 256;
            float v0 = acc0[reg] + b2c + hbw[r0o + colw];
            float v1 = acc1[reg] + b2c + hbw[r1o + colw];
            hbw[r0o + colw] = v0;
            hbw[r1o + colw] = v1;
            hbw[r0o + 128 + colw] = 0.0f;
            hbw[r1o + 128 + colw] = 0.0f;
            store_split(a_hi, a_lo, rr, colw, v0);
            store_split(a_hi, a_lo, rr + 32, colw, v1);
        }
    }
    __syncthreads();

    // stage 3: projection for next layer
    f32x16 aA0, aA1, aB0, aB1;
    #pragma unroll
    for (int i = 0; i < 16; ++i) { aA0[i]=0.f; aA1[i]=0.f; aB0[i]=0.f; aB1[i]=0.f; }
    mfma_proj_stage(a_hi, a_lo, pahi, palo, pbhi, pblo, lid, khalf, colw,
                    aA0, aA1, aB0, aB1);
    float bcol = b1n[colw];
    #pragma unroll
    for (int reg = 0; reg < 16; ++reg) {
        int rr = (reg & 3) + ((reg >> 2) << 3) + (khalf << 2);
        size_t r0o = (size_t)(row0 + rr) * 256;
        size_t r1o = (size_t)(row0 + rr + 32) * 256;
        P[r0o + colw]       = aA0[reg] + bcol;
        P[r1o + colw]       = aA1[reg] + bcol;
        P[r0o + 128 + colw] = aB0[reg];
        P[r1o + 128 + colw] = aB1[reg];
    }
}

// ---------------- chain4 decoder: dw1 -> dw2 -> gw1 -> gw2 ----------------
// out[N,21] = silu((silu(h@dw1+db1)@dw2+db2)@gw1+gb1) @ gw2 + gb2
__global__ __launch_bounds__(256) void chain4_dec_kernel(
    const float* __restrict__ hb,
    const unsigned short* __restrict__ w1hi, const unsigned short* __restrict__ w1lo,
    const float* __restrict__ b1,
    const unsigned short* __restrict__ w2hi, const unsigned short* __restrict__ w2lo,
    const float* __restrict__ b2,
    const unsigned short* __restrict__ w3hi, const unsigned short* __restrict__ w3lo,
    const float* __restrict__ b3,
    const unsigned short* __restrict__ w4hi, const unsigned short* __restrict__ w4lo,
    const float* __restrict__ b4,
    float* __restrict__ out)
{
    __shared__ char a_hi[16384];
    __shared__ char a_lo[16384];

    const int tid   = threadIdx.x;
    const int lane  = tid & 63;
    const int w     = tid >> 6;
    const int row0  = blockIdx.x * 64;
    const int lid   = lane & 31;
    const int khalf = lane >> 5;
    const int colw  = (w << 5) + lid;

    f32x16 acc0, acc1;

    // stage 1: silu(h@dw1 + db1)
    #pragma unroll
    for (int i = 0; i < 16; ++i) { acc0[i] = 0.f; acc1[i] = 0.f; }
    stage_a_chunk(a_hi, a_lo, hb, 256, 128, nullptr, 0, 128, 0, row0, lane, w);
    __syncthreads();
    mfma_chunk(a_hi, a_lo, w1hi, w1lo, 0, 8, lid, khalf, colw, acc0, acc1);
    __syncthreads();
    {
        float bc = b1[colw];
        #pragma unroll
        for (int reg = 0; reg < 16; ++reg) {
            int rr = (reg & 3) + ((reg >> 2) << 3) + (khalf << 2);
            store_split(a_hi, a_lo, rr, colw, silu_f(acc0[reg] + bc));
            store_split(a_hi, a_lo, rr + 32, colw, silu_f(acc1[reg] + bc));
        }
    }
    __syncthreads();

    // stage 2: t2 = @dw2 + db2 (no act)
    #pragma unroll
    for (int i = 0; i < 16; ++i) { acc0[i] = 0.f; acc1[i] = 0.f; }
    mfma_chunk(a_hi, a_lo, w2hi, w2lo, 0, 8, lid, khalf, colw, acc0, acc1);
    __syncthreads();
    {
        float bc = b2[colw];
        #pragma unroll
        for (int reg = 0; reg < 16; ++reg) {
            int rr = (reg & 3) + ((reg >> 2) << 3) + (khalf << 2);
            store_split(a_hi, a_lo, rr, colw, acc0[reg] + bc);
            store_split(a_hi, a_lo, rr + 32, colw, acc1[reg] + bc);
        }
    }
    __syncthreads();

    // stage 3: t3 = silu(t2@gw1 + gb1)
    #pragma unroll
    for (int i = 0; i < 16; ++i) { acc0[i] = 0.f; acc1[i] = 0.f; }
    mfma_chunk(a_hi, a_lo, w3hi, w3lo, 0, 8, lid, khalf, colw, acc0, acc1);
    __syncthreads();
    {
        float bc = b3[colw];
        #pragma unroll
        for (int reg = 0; reg < 16; ++reg) {
            int rr = (reg & 3) + ((reg >> 2) << 3) + (khalf << 2);
            store_split(a_hi, a_lo, rr, colw, silu_f(acc0[reg] + bc));
            store_split(a_hi, a_lo, rr + 32, colw, silu_f(acc1[reg] + bc));
        }
    }
    __syncthreads();

    // stage 4: out = t3@gw2 + gb2 (cols 0..20)
    #pragma unroll
    for (int i = 0; i < 16; ++i) { acc0[i] = 0.f; acc1[i] = 0.f; }
    mfma_chunk(a_hi, a_lo, w4hi, w4lo, 0, 8, lid, khalf, colw, acc0, acc1);
    if (colw < NOUT) {
        float bc = b4[colw];
        #pragma unroll
        for (int reg = 0; reg < 16; ++reg) {
            int rr = (reg & 3) + ((reg >> 2) << 3) + (khalf << 2);
            out[(size_t)(row0 + rr) * NOUT + colw]      = acc0[reg] + bc;
            out[(size_t)(row0 + rr + 32) * NOUT + colw] = acc1[reg] + bc;
        }
    }
}

// ---------------- fused edge kernel (R12 known-good 64-edge structure) -----
__global__ __launch_bounds__(256) void edge_kernel(
    const float* __restrict__ P,
    const int* __restrict__ srow, const int* __restrict__ scol,
    const float* __restrict__ srad, const float* __restrict__ sea,
    const unsigned short* __restrict__ w2tb_hi,
    const unsigned short* __restrict__ w2tb_lo,
    const float* __restrict__ b2,
    const float* __restrict__ wr, const float* __restrict__ we,
    float* __restrict__ hb)
{
    __shared__ char smem[64 * 132 * 4];
    __shared__ int   s_row[64];
    __shared__ int   s_col[64];
    __shared__ float s_rad[64];
    __shared__ float s_ea4[64 * 4];
    __shared__ int   s_segstart[66];
    __shared__ int   s_nseg;

    char* a_hi = smem;
    char* a_lo = smem + 16384;
    float* s_ef = (float*)smem;

    const int tid  = threadIdx.x;
    const int lane = tid & 63;
    const int w    = tid >> 6;
    const int p0   = blockIdx.x * 64;

    if (tid < 64) {
        s_row[tid] = srow[p0 + tid];
        s_col[tid] = scol[p0 + tid];
        s_rad[tid] = srad[p0 + tid];
        *(float4*)&s_ea4[tid * 4] = *(const float4*)&sea[(size_t)(p0 + tid) * 4];
    }
    __syncthreads();

    if (tid < 64) {
        bool flag = (tid == 0) || (s_row[tid] != s_row[tid - 1]);
        unsigned long long mask = __ballot(flag);
        int idx = __popcll(mask & ((1ull << tid) - 1));
        if (flag) s_segstart[idx] = tid;
        if (tid == 0) { int ns = __popcll(mask); s_nseg = ns; s_segstart[ns] = 64; }
    }

    // phase 1: pre1 -> silu -> split bf16 -> LDS (vec2 packed math)
    const int k2 = lane * 2;
    const vf2 wrv = *(const vf2*)&wr[k2];
    const vf2 wa0 = *(const vf2*)&we[0 * 128 + k2];
    const vf2 wa1 = *(const vf2*)&we[1 * 128 + k2];
    const vf2 wa2 = *(const vf2*)&we[2 * 128 + k2];
    const vf2 wa3 = *(const vf2*)&we[3 * 128 + k2];
    #pragma unroll 4
    for (int it = 0; it < 16; ++it) {
        int et = it * 4 + w;
        int r = s_row[et], c = s_col[et];
        float rad = s_rad[et];
        float4 ea = *(const float4*)&s_ea4[et * 4];
        vf2 ps = *(const vf2*)&P[(size_t)r * 256 + k2];
        vf2 pt = *(const vf2*)&P[(size_t)c * 256 + 128 + k2];
        vf2 pre = ps + pt;
        pre += rad * wrv;
        pre += ea.x * wa0;
        pre += ea.y * wa1;
        pre += ea.z * wa2;
        pre += ea.w * wa3;
        vf2 sl;
        sl.x = silu_f(pre.x);
        sl.y = silu_f(pre.y);
        unsigned hi2, lo2;
        split2v(sl, hi2, lo2);
        int byte = (et * 256 + lane * 4) ^ ((et & 7) << 4);
        *(unsigned*)(a_hi + byte) = hi2;
        *(unsigned*)(a_lo + byte) = lo2;
    }
    __syncthreads();

    // phase 2: [64x128] @ [128x128] split-bf16 MFMA (B streamed via L1)
    const int lid   = lane & 31;
    const int khalf = lane >> 5;
    const int colw  = (w << 5) + lid;
    f32x16 acc0, acc1;
    #pragma unroll
    for (int i = 0; i < 16; ++i) { acc0[i] = 0.f; acc1[i] = 0.f; }
    mfma_chunk(a_hi, a_lo, w2tb_hi, w2tb_lo, 0, 8, lid, khalf, colw, acc0, acc1);
    __syncthreads();

    // phase 2b: silu(acc + b2) -> s_ef (f32, 132-stride)
    float bcol = b2[colw];
    #pragma unroll
    for (int reg = 0; reg < 16; ++reg) {
        int rr = (reg & 3) + ((reg >> 2) << 3) + (khalf << 2);
        s_ef[rr * 132 + colw]        = silu_f(acc0[reg] + bcol);
        s_ef[(rr + 32) * 132 + colw] = silu_f(acc1[reg] + bcol);
    }
    __syncthreads();

    // phase 3: segmented reduce; interior rows -> store, boundary -> atomics
    const int jg = tid & 31, rg = tid >> 5;
    const int j = jg * 4;
    const int nseg = s_nseg;
    for (int s = rg; s < nseg; s += 8) {
        int sp0 = s_segstart[s], sp1 = s_segstart[s + 1];
        float v0 = 0.f, v1 = 0.f, v2 = 0.f, v3 = 0.f;
        for (int p = sp0; p < sp1; ++p) {
            float4 q = *(const float4*)&s_ef[p * 132 + j];
            v0 += q.x; v1 += q.y; v2 += q.z; v3 += q.w;
        }
        int rowId = s_row[sp0];
        bool interior = true;
        if (sp0 == 0 && p0 > 0 && srow[p0 - 1] == rowId) interior = false;
        if (sp1 == 64 && p0 + 64 < N_EDGES && srow[p0 + 64] == rowId) interior = false;
        float* dst = &hb[(size_t)rowId * 256 + 128 + j];
        if (interior) {
            *(float4*)dst = make_float4(v0, v1, v2, v3);
        } else {
            atomicAdd(&dst[0], v0); atomicAdd(&dst[1], v1);
            atomicAdd(&dst[2], v2); atomicAdd(&dst[3], v3);
        }
    }
}

extern "C" void kernel_launch(void* const* d_in, const int* in_sizes, int n_in,
                              void* d_out, int out_size, void* d_ws, size_t ws_size,
                              hipStream_t stream)
{
    const float* h0       = (const float*)d_in[0];
    const float* x        = (const float*)d_in[1];
    const int*   edges    = (const int*)  d_in[2];
    const float* edge_attr= (const float*)d_in[3];
    const float* emb_w    = (const float*)d_in[4];
    const float* emb_b    = (const float*)d_in[5];
    const float* ew1      = (const float*)d_in[6];
    const float* eb1      = (const float*)d_in[7];
    const float* ew2      = (const float*)d_in[8];
    const float* eb2      = (const float*)d_in[9];
    const float* nw1      = (const float*)d_in[10];
    const float* nb1      = (const float*)d_in[11];
    const float* nw2      = (const float*)d_in[12];
    const float* nb2      = (const float*)d_in[13];
    const float* dw1      = (const float*)d_in[14];
    const float* db1      = (const float*)d_in[15];
    const float* dw2      = (const float*)d_in[16];
    const float* db2      = (const float*)d_in[17];
    const float* gw1      = (const float*)d_in[18];
    const float* gb1      = (const float*)d_in[19];
    const float* gw2      = (const float*)d_in[20];
    const float* gb2      = (const float*)d_in[21];
    float* out = (float*)d_out;

    char* ws = (char*)d_ws;
    const size_t SZ_HB = (size_t)N_NODES * 256 * 4;
    const size_t SZ_T  = (size_t)N_NODES * HID * 4;
    const size_t SZ_E  = (size_t)N_EDGES * 4;
    float* hb     = (float*)(ws);                       // [N,256] = [h | agg]
    float* P      = (float*)(ws + SZ_HB);               // [N,256]
    char*  base   = ws + SZ_HB * 2 + SZ_T;
    float* radial = (float*)(base);                     // dead after scatter
    int*   s_row  = (int*)  (base + SZ_E);
    int*   s_col  = (int*)  (base + SZ_E * 2);
    float* s_rad  = (float*)(base + SZ_E * 3);
    float* s_ea   = (float*)(base + SZ_E * 4);
    int*   rowptr = (int*)  (base + SZ_E * 8);
    int*   cnt    = (int*)  (base + SZ_E * 8 + (N_NODES + 64) * 4);
    unsigned short* w_hi = (unsigned short*)radial;
    unsigned short* w_lo = w_hi + W_TOTAL;

    const int* erow = edges;
    const int* ecol = edges + N_EDGES;

    radial_kernel<<<N_EDGES / 256, 256, 0, stream>>>(x, erow, ecol, radial);

    hipMemsetAsync(cnt, 0, N_NODES * 4, stream);
    hist_kernel<<<N_EDGES / 256, 256, 0, stream>>>(erow, cnt);
    scan_kernel<<<1, 1024, 0, stream>>>(cnt, rowptr);
    hipMemsetAsync(cnt, 0, N_NODES * 4, stream);
    scatter_kernel<<<N_EDGES / 256, 256, 0, stream>>>(
        erow, ecol, radial, edge_attr, rowptr, cnt, s_row, s_col, s_rad, s_ea);

    prep_all_kernel<<<dim3(136, 25), 256, 0, stream>>>(
        ew1, ew2, nw1, nw2, dw1, dw2, gw1, emb_w, gw2, w_hi, w_lo);

    // fused: h = h0@emb_w+emb_b ; layer-0 projection ; agg zero
    emb_proj_kernel<<<625, 256, 0, stream>>>(
        h0, w_hi + OFF_EMB, w_lo + OFF_EMB, emb_b,
        w_hi + OFF_W1A, w_lo + OFF_W1A, w_hi + OFF_W1B, w_lo + OFF_W1B,
        eb1, hb, P);

    for (int l = 0; l < NLAYERS; ++l) {
        const float* W1   = ew1 + (size_t)l * 261 * 128;
        const float* b2v  = eb2 + l * 128;
        const float* nb1v = nb1 + l * 128;
        const float* nb2v = nb2 + l * 128;

        edge_kernel<<<N_EDGES / 64, 256, 0, stream>>>(
            P, s_row, s_col, s_rad, s_ea,
            w_hi + OFF_W2 + (size_t)l * 16384, w_lo + OFF_W2 + (size_t)l * 16384,
            b2v, W1 + 256 * 128, W1 + 257 * 128, hb);

        if (l < NLAYERS - 1) {
            chain3_node_kernel<<<625, 256, 0, stream>>>(
                hb, h0,
                w_hi + OFF_NW1 + l * 34816, w_lo + OFF_NW1 + l * 34816, nb1v,
                w_hi + OFF_NW2 + l * 16384, w_lo + OFF_NW2 + l * 16384, nb2v,
                w_hi + OFF_W1A + (l + 1) * 16384, w_lo + OFF_W1A + (l + 1) * 16384,
                w_hi + OFF_W1B + (l + 1) * 16384, w_lo + OFF_W1B + (l + 1) * 16384,
                eb1 + (l + 1) * 128,
                hb, P);
        } else {
            mfma_chain2_kernel<<<625, 256, 0, stream>>>(
                hb, 256, 256, h0, F_IN, 271,
                w_hi + OFF_NW1 + l * 34816, w_lo + OFF_NW1 + l * 34816,
                nb1v, FLAG_BIAS | FLAG_SILU,
                w_hi + OFF_NW2 + l * 16384, w_lo + OFF_NW2 + l * 16384,
                nb2v, FLAG_BIAS | FLAG_ACC,
                hb, 256);
        }
    }

    // decoder: all four GEMMs in one kernel, writes out[N,21] directly
    chain4_dec_kernel<<<625, 256, 0, stream>>>(
        hb,
        w_hi + OFF_DW1, w_lo + OFF_DW1, db1,
        w_hi + OFF_DW2, w_lo + OFF_DW2, db2,
        w_hi + OFF_GW1, w_lo + OFF_GW1, gb1,
        w_hi + OFF_GW2, w_lo + OFF_GW2, gb2,
        out);
}

// Round 15
// 767.352 us; speedup vs baseline: 1.2785x; 1.0906x over previous
//
#include <hip/hip_runtime.h>
#include <hip/hip_bf16.h>
#include <math.h>

#define N_NODES 40000
#define N_EDGES 640000
#define F_IN    15
#define HID     128
#define NLAYERS 4
#define NOUT    21

#define FLAG_BIAS 1
#define FLAG_ACC  2
#define FLAG_SILU 4

typedef __attribute__((ext_vector_type(8))) short bf16x8;
typedef __attribute__((ext_vector_type(16))) float f32x16;
typedef __attribute__((ext_vector_type(2)))  float vf2;

__device__ __forceinline__ float silu_f(float x) {
    return x * __builtin_amdgcn_rcpf(1.0f + __expf(-x));
}

__device__ __forceinline__ unsigned short f2bf(float f) {
    unsigned u = __builtin_bit_cast(unsigned, f);
    unsigned r = (u + 0x7FFFu + ((u >> 16) & 1u)) >> 16;
    return (unsigned short)r;
}
__device__ __forceinline__ float bf2f(unsigned short b) {
    return __builtin_bit_cast(float, (unsigned)b << 16);
}

__device__ __forceinline__ void split2v(vf2 v, unsigned& hi2, unsigned& lo2) {
    union { __hip_bfloat162 b; unsigned u; } ch, cl;
    ch.b = __float22bfloat162_rn(make_float2(v.x, v.y));
    vf2 h;
    h.x = __builtin_bit_cast(float, ch.u << 16);
    h.y = __builtin_bit_cast(float, ch.u & 0xFFFF0000u);
    vf2 r = v - h;
    cl.b = __float22bfloat162_rn(make_float2(r.x, r.y));
    hi2 = ch.u;
    lo2 = cl.u;
}

__device__ __forceinline__ void store_split(char* a_hi, char* a_lo, int row, int col, float v) {
    unsigned short h = f2bf(v);
    unsigned short l = f2bf(v - bf2f(h));
    int byte = (row * 256 + col * 2) ^ ((row & 7) << 4);
    *(unsigned short*)(a_hi + byte) = h;
    *(unsigned short*)(a_lo + byte) = l;
}

// ---------------- CSR build ----------------
__global__ __launch_bounds__(256) void hist_kernel(
    const int* __restrict__ erow, int* __restrict__ cnt)
{
    int e = blockIdx.x * 256 + threadIdx.x;
    if (e < N_EDGES) atomicAdd(&cnt[erow[e]], 1);
}

// multi-block scan, level 1: per-1024-block inclusive scan + block sum; zero cnt
__global__ __launch_bounds__(1024) void scan1_kernel(
    int* __restrict__ cnt, int* __restrict__ incl, int* __restrict__ bsum)
{
    __shared__ int s[1024];
    const int b = blockIdx.x, tid = threadIdx.x;
    const int i = b * 1024 + tid;
    int v = (i < N_NODES) ? cnt[i] : 0;
    s[tid] = v;
    __syncthreads();
    for (int off = 1; off < 1024; off <<= 1) {
        int t = (tid >= off) ? s[tid - off] : 0;
        __syncthreads();
        s[tid] += t;
        __syncthreads();
    }
    if (i < N_NODES) { incl[i] = s[tid]; cnt[i] = 0; }   // zero for fill reuse
    if (tid == 1023) bsum[b] = s[1023];
}

__global__ __launch_bounds__(64) void scan2_kernel(
    const int* __restrict__ bsum, int* __restrict__ boff, int* __restrict__ rowptr)
{
    if (threadIdx.x == 0) {
        int acc = 0;
        for (int b = 0; b < 40; ++b) { boff[b] = acc; acc += bsum[b]; }
        rowptr[0] = 0;
    }
}

__global__ __launch_bounds__(1024) void scan3_kernel(
    const int* __restrict__ incl, const int* __restrict__ boff,
    int* __restrict__ rowptr)
{
    const int b = blockIdx.x, tid = threadIdx.x;
    const int i = b * 1024 + tid;
    if (i < N_NODES) rowptr[i + 1] = incl[i] + boff[b];
}

// scatter with inline radial computation
__global__ __launch_bounds__(256) void scatter_kernel(
    const float* __restrict__ x,
    const int* __restrict__ erow, const int* __restrict__ ecol,
    const float* __restrict__ edge_attr,
    const int* __restrict__ rowptr, int* __restrict__ fill,
    int* __restrict__ srow, int* __restrict__ scol,
    float* __restrict__ srad, float* __restrict__ sea)
{
    int e = blockIdx.x * 256 + threadIdx.x;
    if (e >= N_EDGES) return;
    int r = erow[e], c = ecol[e];
    float dx = x[r*3+0] - x[c*3+0];
    float dy = x[r*3+1] - x[c*3+1];
    float dz = x[r*3+2] - x[c*3+2];
    int pos = rowptr[r] + atomicAdd(&fill[r], 1);
    srow[pos] = r;
    scol[pos] = c;
    srad[pos] = dx*dx + dy*dy + dz*dz;
    float4 ea = *(const float4*)&edge_attr[(size_t)e * 4];
    *(float4*)&sea[(size_t)pos * 4] = ea;
}

// ---------------- unified weight split/transpose prep ----------------
#define OFF_W2   0
#define OFF_W1A  65536
#define OFF_W1B  131072
#define OFF_NW1  196608
#define OFF_NW2  335872
#define OFF_DW1  401408
#define OFF_DW2  417792
#define OFF_GW1  434176
#define OFF_EMB  450560
#define OFF_GW2  452608
#define W_TOTAL  468992

__global__ __launch_bounds__(256) void prep_all_kernel(
    const float* __restrict__ ew1, const float* __restrict__ ew2,
    const float* __restrict__ nw1, const float* __restrict__ nw2,
    const float* __restrict__ dw1, const float* __restrict__ dw2,
    const float* __restrict__ gw1, const float* __restrict__ emb_w,
    const float* __restrict__ gw2,
    unsigned short* __restrict__ hi, unsigned short* __restrict__ lo)
{
    const int T = blockIdx.y;
    int srcSel, srcOff, K, dstOff;
    if (T < 4)       { srcSel=1; srcOff=T*16384;           K=128; dstOff=OFF_W2 +T*16384; }
    else if (T < 8)  { int l=T-4;  srcSel=0; srcOff=l*33408;        K=128; dstOff=OFF_W1A+l*16384; }
    else if (T < 12) { int l=T-8;  srcSel=0; srcOff=l*33408+16384;  K=128; dstOff=OFF_W1B+l*16384; }
    else if (T < 16) { int l=T-12; srcSel=2; srcOff=l*34688;        K=271; dstOff=OFF_NW1+l*34816; }
    else if (T < 20) { int l=T-16; srcSel=3; srcOff=l*16384;        K=128; dstOff=OFF_NW2+l*16384; }
    else if (T == 20){ srcSel=4; srcOff=0; K=128; dstOff=OFF_DW1; }
    else if (T == 21){ srcSel=5; srcOff=0; K=128; dstOff=OFF_DW2; }
    else if (T == 22){ srcSel=6; srcOff=0; K=128; dstOff=OFF_GW1; }
    else if (T == 23){ srcSel=7; srcOff=0; K=15;  dstOff=OFF_EMB; }
    else             { srcSel=8; srcOff=0; K=128; dstOff=OFF_GW2; }

    const float* src;
    switch (srcSel) {
        case 0: src = ew1; break;  case 1: src = ew2; break;
        case 2: src = nw1; break;  case 3: src = nw2; break;
        case 4: src = dw1; break;  case 5: src = dw2; break;
        case 6: src = gw1; break;  case 7: src = emb_w; break;
        default: src = gw2; break;
    }
    int K16 = (K + 15) & ~15;
    int idx = blockIdx.x * 256 + threadIdx.x;
    if (idx >= K16 * 128) return;
    int k = idx >> 7, c = idx & 127;
    float v = 0.0f;
    if (k < K) {
        if (srcSel == 8) { if (c < NOUT) v = src[k * NOUT + c]; }
        else v = src[srcOff + k * 128 + c];
    }
    unsigned short h = f2bf(v);
    unsigned short lw = f2bf(v - bf2f(h));
    int o = dstOff + ((k >> 3) << 10) + (c << 3) + (k & 7);
    hi[o] = h; lo[o] = lw;
}

// ---------------- shared MFMA helpers ----------------
__device__ __forceinline__ void stage_a_chunk(
    char* a_hi, char* a_lo,
    const float* __restrict__ A1, int lda1, int KA1,
    const float* __restrict__ A2, int lda2, int KA,
    int kc, int row0, int lane, int w)
{
    if (kc + 128 <= KA1) {
        #pragma unroll 4
        for (int it = 0; it < 16; ++it) {
            int row = it * 4 + w;
            vf2 v = *(const vf2*)&A1[(size_t)(row0 + row) * lda1 + kc + lane * 2];
            unsigned hi2, lo2;
            split2v(v, hi2, lo2);
            int byte = (row * 256 + lane * 4) ^ ((row & 7) << 4);
            *(unsigned*)(a_hi + byte) = hi2;
            *(unsigned*)(a_lo + byte) = lo2;
        }
    } else {
        for (int it = 0; it < 16; ++it) {
            int row = it * 4 + w;
            vf2 vv;
            #pragma unroll
            for (int d = 0; d < 2; ++d) {
                int k = kc + lane * 2 + d;
                float v = 0.0f;
                if (k < KA1) v = A1[(size_t)(row0 + row) * lda1 + k];
                else if (k < KA) v = A2[(size_t)(row0 + row) * lda2 + (k - KA1)];
                vv[d] = v;
            }
            unsigned hi2, lo2;
            split2v(vv, hi2, lo2);
            int byte = (row * 256 + lane * 4) ^ ((row & 7) << 4);
            *(unsigned*)(a_hi + byte) = hi2;
            *(unsigned*)(a_lo + byte) = lo2;
        }
    }
}

__device__ __forceinline__ void mfma_chunk(
    const char* a_hi, const char* a_lo,
    const unsigned short* __restrict__ bhi, const unsigned short* __restrict__ blo,
    int kc, int nks, int lid, int khalf, int colw,
    f32x16& acc0, f32x16& acc1)
{
    const int sw0 = (lid & 7) << 4;
    for (int ks = 0; ks < nks; ++ks) {
        int ab = (lid * 256 + ks * 32 + khalf * 16) ^ sw0;
        bf16x8 ah0 = *(const bf16x8*)(a_hi + ab);
        bf16x8 al0 = *(const bf16x8*)(a_lo + ab);
        bf16x8 ah1 = *(const bf16x8*)(a_hi + ab + 8192);
        bf16x8 al1 = *(const bf16x8*)(a_lo + ab + 8192);
        int slot = (kc >> 3) + (ks << 1) + khalf;
        bf16x8 bh = *(const bf16x8*)(bhi + (slot << 10) + (colw << 3));
        bf16x8 bl = *(const bf16x8*)(blo + (slot << 10) + (colw << 3));
        acc0 = __builtin_amdgcn_mfma_f32_32x32x16_bf16(ah0, bh, acc0, 0, 0, 0);
        acc1 = __builtin_amdgcn_mfma_f32_32x32x16_bf16(ah1, bh, acc1, 0, 0, 0);
        acc0 = __builtin_amdgcn_mfma_f32_32x32x16_bf16(ah0, bl, acc0, 0, 0, 0);
        acc1 = __builtin_amdgcn_mfma_f32_32x32x16_bf16(ah1, bl, acc1, 0, 0, 0);
        acc0 = __builtin_amdgcn_mfma_f32_32x32x16_bf16(al0, bh, acc0, 0, 0, 0);
        acc1 = __builtin_amdgcn_mfma_f32_32x32x16_bf16(al1, bh, acc1, 0, 0, 0);
    }
}

// dual-B MFMA over the staged 128-chunk (for projections)
__device__ __forceinline__ void mfma_proj_stage(
    const char* a_hi, const char* a_lo,
    const unsigned short* __restrict__ wahi, const unsigned short* __restrict__ walo,
    const unsigned short* __restrict__ wbhi, const unsigned short* __restrict__ wblo,
    int lid, int khalf, int colw,
    f32x16& aA0, f32x16& aA1, f32x16& aB0, f32x16& aB1)
{
    const int sw0 = (lid & 7) << 4;
    #pragma unroll 2
    for (int ks = 0; ks < 8; ++ks) {
        int ab = (lid * 256 + ks * 32 + khalf * 16) ^ sw0;
        bf16x8 ah0 = *(const bf16x8*)(a_hi + ab);
        bf16x8 al0 = *(const bf16x8*)(a_lo + ab);
        bf16x8 ah1 = *(const bf16x8*)(a_hi + ab + 8192);
        bf16x8 al1 = *(const bf16x8*)(a_lo + ab + 8192);
        int slot = (ks << 1) + khalf;
        bf16x8 bah = *(const bf16x8*)(wahi + (slot << 10) + (colw << 3));
        bf16x8 bal = *(const bf16x8*)(walo + (slot << 10) + (colw << 3));
        bf16x8 bbh = *(const bf16x8*)(wbhi + (slot << 10) + (colw << 3));
        bf16x8 bbl = *(const bf16x8*)(wblo + (slot << 10) + (colw << 3));
        aA0 = __builtin_amdgcn_mfma_f32_32x32x16_bf16(ah0, bah, aA0, 0, 0, 0);
        aA1 = __builtin_amdgcn_mfma_f32_32x32x16_bf16(ah1, bah, aA1, 0, 0, 0);
        aB0 = __builtin_amdgcn_mfma_f32_32x32x16_bf16(ah0, bbh, aB0, 0, 0, 0);
        aB1 = __builtin_amdgcn_mfma_f32_32x32x16_bf16(ah1, bbh, aB1, 0, 0, 0);
        aA0 = __builtin_amdgcn_mfma_f32_32x32x16_bf16(ah0, bal, aA0, 0, 0, 0);
        aA1 = __builtin_amdgcn_mfma_f32_32x32x16_bf16(ah1, bal, aA1, 0, 0, 0);
        aB0 = __builtin_amdgcn_mfma_f32_32x32x16_bf16(ah0, bbl, aB0, 0, 0, 0);
        aB1 = __builtin_amdgcn_mfma_f32_32x32x16_bf16(ah1, bbl, aB1, 0, 0, 0);
        aA0 = __builtin_amdgcn_mfma_f32_32x32x16_bf16(al0, bah, aA0, 0, 0, 0);
        aA1 = __builtin_amdgcn_mfma_f32_32x32x16_bf16(al1, bah, aA1, 0, 0, 0);
        aB0 = __builtin_amdgcn_mfma_f32_32x32x16_bf16(al0, bbh, aB0, 0, 0, 0);
        aB1 = __builtin_amdgcn_mfma_f32_32x32x16_bf16(al1, bbh, aB1, 0, 0, 0);
    }
}

// ---------------- emb + layer-0 projection fused ----------------
__global__ __launch_bounds__(256) void emb_proj_kernel(
    const float* __restrict__ h0,
    const unsigned short* __restrict__ ehi, const unsigned short* __restrict__ elo,
    const float* __restrict__ emb_b,
    const unsigned short* __restrict__ wahi, const unsigned short* __restrict__ walo,
    const unsigned short* __restrict__ wbhi, const unsigned short* __restrict__ wblo,
    const float* __restrict__ b1,
    float* __restrict__ hbw, float* __restrict__ P)
{
    __shared__ char a_hi[16384];
    __shared__ char a_lo[16384];

    const int tid   = threadIdx.x;
    const int lane  = tid & 63;
    const int w     = tid >> 6;
    const int row0  = blockIdx.x * 64;
    const int lid   = lane & 31;
    const int khalf = lane >> 5;
    const int colw  = (w << 5) + lid;

    // stage h0 tile: 64 rows x 16 cols (col 15 zero-padded)
    {
        int row = tid >> 2;
        int c0 = (tid & 3) * 4;
        const float* srcp = &h0[(size_t)(row0 + row) * F_IN];
        vf2 vA, vB;
        vA.x = srcp[c0 + 0];
        vA.y = srcp[c0 + 1];
        vB.x = srcp[c0 + 2];
        vB.y = (c0 + 3 < F_IN) ? srcp[c0 + 3] : 0.0f;
        unsigned h2, l2;
        split2v(vA, h2, l2);
        int byteA = (row * 256 + c0 * 2) ^ ((row & 7) << 4);
        *(unsigned*)(a_hi + byteA) = h2;
        *(unsigned*)(a_lo + byteA) = l2;
        split2v(vB, h2, l2);
        int byteB = (row * 256 + c0 * 2 + 4) ^ ((row & 7) << 4);
        *(unsigned*)(a_hi + byteB) = h2;
        *(unsigned*)(a_lo + byteB) = l2;
    }
    __syncthreads();

    // emb: K=16 (one k16-slice)
    f32x16 acc0, acc1;
    #pragma unroll
    for (int i = 0; i < 16; ++i) { acc0[i] = 0.f; acc1[i] = 0.f; }
    mfma_chunk(a_hi, a_lo, ehi, elo, 0, 1, lid, khalf, colw, acc0, acc1);
    __syncthreads();

    // h -> hb cols 0..127 and split into LDS
    {
        float bc = emb_b[colw];
        #pragma unroll
        for (int reg = 0; reg < 16; ++reg) {
            int rr = (reg & 3) + ((reg >> 2) << 3) + (khalf << 2);
            size_t r0o = (size_t)(row0 + rr) * 256;
            size_t r1o = (size_t)(row0 + rr + 32) * 256;
            float v0 = acc0[reg] + bc;
            float v1 = acc1[reg] + bc;
            hbw[r0o + colw] = v0;
            hbw[r1o + colw] = v1;
            store_split(a_hi, a_lo, rr, colw, v0);
            store_split(a_hi, a_lo, rr + 32, colw, v1);
        }
    }
    __syncthreads();

    // layer-0 projection + agg zero
    f32x16 aA0, aA1, aB0, aB1;
    #pragma unroll
    for (int i = 0; i < 16; ++i) { aA0[i]=0.f; aA1[i]=0.f; aB0[i]=0.f; aB1[i]=0.f; }
    mfma_proj_stage(a_hi, a_lo, wahi, walo, wbhi, wblo, lid, khalf, colw,
                    aA0, aA1, aB0, aB1);

    float bcol = b1[colw];
    #pragma unroll
    for (int reg = 0; reg < 16; ++reg) {
        int rr = (reg & 3) + ((reg >> 2) << 3) + (khalf << 2);
        size_t r0o = (size_t)(row0 + rr) * 256;
        size_t r1o = (size_t)(row0 + rr + 32) * 256;
        P[r0o + colw]       = aA0[reg] + bcol;
        P[r1o + colw]       = aA1[reg] + bcol;
        P[r0o + 128 + colw] = aB0[reg];
        P[r1o + 128 + colw] = aB1[reg];
        hbw[r0o + 128 + colw] = 0.0f;
        hbw[r1o + 128 + colw] = 0.0f;
    }
}

// ---------------- chained 2-stage MFMA GEMM (layer-3 node MLP) ------------
__global__ __launch_bounds__(256) void mfma_chain2_kernel(
    const float* __restrict__ A1, int lda1, int KA1,
    const float* __restrict__ A2, int lda2, int KA,
    const unsigned short* __restrict__ w1hi, const unsigned short* __restrict__ w1lo,
    const float* __restrict__ bias1, int flags1,
    const unsigned short* __restrict__ w2hi, const unsigned short* __restrict__ w2lo,
    const float* __restrict__ bias2, int flags2,
    float* __restrict__ out, int ldout)
{
    __shared__ char a_hi[16384];
    __shared__ char a_lo[16384];

    const int tid   = threadIdx.x;
    const int lane  = tid & 63;
    const int w     = tid >> 6;
    const int row0  = blockIdx.x * 64;
    const int lid   = lane & 31;
    const int khalf = lane >> 5;
    const int colw  = (w << 5) + lid;
    const int K16   = (KA + 15) & ~15;

    f32x16 acc0, acc1;
    #pragma unroll
    for (int i = 0; i < 16; ++i) { acc0[i] = 0.f; acc1[i] = 0.f; }

    for (int kc = 0; kc < K16; kc += 128) {
        int CK = K16 - kc; if (CK > 128) CK = 128;
        __syncthreads();
        stage_a_chunk(a_hi, a_lo, A1, lda1, KA1, A2, lda2, KA, kc, row0, lane, w);
        __syncthreads();
        mfma_chunk(a_hi, a_lo, w1hi, w1lo, kc, CK >> 4, lid, khalf, colw, acc0, acc1);
    }

    __syncthreads();
    {
        float b1c = (flags1 & FLAG_BIAS) ? bias1[colw] : 0.0f;
        #pragma unroll
        for (int reg = 0; reg < 16; ++reg) {
            int rr = (reg & 3) + ((reg >> 2) << 3) + (khalf << 2);
            float v0 = acc0[reg] + b1c;
            float v1 = acc1[reg] + b1c;
            if (flags1 & FLAG_SILU) { v0 = silu_f(v0); v1 = silu_f(v1); }
            store_split(a_hi, a_lo, rr, colw, v0);
            store_split(a_hi, a_lo, rr + 32, colw, v1);
        }
    }
    __syncthreads();

    #pragma unroll
    for (int i = 0; i < 16; ++i) { acc0[i] = 0.f; acc1[i] = 0.f; }
    mfma_chunk(a_hi, a_lo, w2hi, w2lo, 0, 8, lid, khalf, colw, acc0, acc1);

    float bcol = (flags2 & FLAG_BIAS) ? bias2[colw] : 0.0f;
    #pragma unroll
    for (int reg = 0; reg < 16; ++reg) {
        int rr = (reg & 3) + ((reg >> 2) << 3) + (khalf << 2);
        float v0 = acc0[reg] + bcol;
        float v1 = acc1[reg] + bcol;
        float* p0 = &out[(size_t)(row0 + rr) * ldout + colw];
        float* p1 = &out[(size_t)(row0 + rr + 32) * ldout + colw];
        if (flags2 & FLAG_ACC) { v0 += *p0; v1 += *p1; }
        if (flags2 & FLAG_SILU) { v0 = silu_f(v0); v1 = silu_f(v1); }
        *p0 = v0; *p1 = v1;
    }
}

// ---------------- chain3: node MLP (l) + projection (l+1) + agg zero ------
__global__ __launch_bounds__(256) void chain3_node_kernel(
    const float* __restrict__ hb, const float* __restrict__ h0,
    const unsigned short* __restrict__ w1hi, const unsigned short* __restrict__ w1lo,
    const float* __restrict__ nb1v,
    const unsigned short* __restrict__ w2hi, const unsigned short* __restrict__ w2lo,
    const float* __restrict__ nb2v,
    const unsigned short* __restrict__ pahi, const unsigned short* __restrict__ palo,
    const unsigned short* __restrict__ pbhi, const unsigned short* __restrict__ pblo,
    const float* __restrict__ b1n,
    float* __restrict__ hbw, float* __restrict__ P)
{
    __shared__ char a_hi[16384];
    __shared__ char a_lo[16384];

    const int tid   = threadIdx.x;
    const int lane  = tid & 63;
    const int w     = tid >> 6;
    const int row0  = blockIdx.x * 64;
    const int lid   = lane & 31;
    const int khalf = lane >> 5;
    const int colw  = (w << 5) + lid;

    // stage 1: silu([hb|h0]@nw1 + nb1), K=271
    f32x16 acc0, acc1;
    #pragma unroll
    for (int i = 0; i < 16; ++i) { acc0[i] = 0.f; acc1[i] = 0.f; }
    for (int kc = 0; kc < 272; kc += 128) {
        int CK = 272 - kc; if (CK > 128) CK = 128;
        __syncthreads();
        stage_a_chunk(a_hi, a_lo, hb, 256, 256, h0, F_IN, 271, kc, row0, lane, w);
        __syncthreads();
        mfma_chunk(a_hi, a_lo, w1hi, w1lo, kc, CK >> 4, lid, khalf, colw, acc0, acc1);
    }
    __syncthreads();
    {
        float b1c = nb1v[colw];
        #pragma unroll
        for (int reg = 0; reg < 16; ++reg) {
            int rr = (reg & 3) + ((reg >> 2) << 3) + (khalf << 2);
            store_split(a_hi, a_lo, rr, colw, silu_f(acc0[reg] + b1c));
            store_split(a_hi, a_lo, rr + 32, colw, silu_f(acc1[reg] + b1c));
        }
    }
    __syncthreads();

    // stage 2: h' = h + (t1@nw2 + nb2); write h'; zero agg; split h' into LDS
    #pragma unroll
    for (int i = 0; i < 16; ++i) { acc0[i] = 0.f; acc1[i] = 0.f; }
    mfma_chunk(a_hi, a_lo, w2hi, w2lo, 0, 8, lid, khalf, colw, acc0, acc1);
    __syncthreads();
    {
        float b2c = nb2v[colw];
        #pragma unroll
        for (int reg = 0; reg < 16; ++reg) {
            int rr = (reg & 3) + ((reg >> 2) << 3) + (khalf << 2);
            size_t r0o = (size_t)(row0 + rr) * 256;
            size_t r1o = (size_t)(row0 + rr + 32) * 256;
            float v0 = acc0[reg] + b2c + hbw[r0o + colw];
            float v1 = acc1[reg] + b2c + hbw[r1o + colw];
            hbw[r0o + colw] = v0;
            hbw[r1o + colw] = v1;
            hbw[r0o + 128 + colw] = 0.0f;
            hbw[r1o + 128 + colw] = 0.0f;
            store_split(a_hi, a_lo, rr, colw, v0);
            store_split(a_hi, a_lo, rr + 32, colw, v1);
        }
    }
    __syncthreads();

    // stage 3: projection for next layer
    f32x16 aA0, aA1, aB0, aB1;
    #pragma unroll
    for (int i = 0; i < 16; ++i) { aA0[i]=0.f; aA1[i]=0.f; aB0[i]=0.f; aB1[i]=0.f; }
    mfma_proj_stage(a_hi, a_lo, pahi, palo, pbhi, pblo, lid, khalf, colw,
                    aA0, aA1, aB0, aB1);
    float bcol = b1n[colw];
    #pragma unroll
    for (int reg = 0; reg < 16; ++reg) {
        int rr = (reg & 3) + ((reg >> 2) << 3) + (khalf << 2);
        size_t r0o = (size_t)(row0 + rr) * 256;
        size_t r1o = (size_t)(row0 + rr + 32) * 256;
        P[r0o + colw]       = aA0[reg] + bcol;
        P[r1o + colw]       = aA1[reg] + bcol;
        P[r0o + 128 + colw] = aB0[reg];
        P[r1o + 128 + colw] = aB1[reg];
    }
}

// ---------------- chain4 decoder: dw1 -> dw2 -> gw1 -> gw2 ----------------
__global__ __launch_bounds__(256) void chain4_dec_kernel(
    const float* __restrict__ hb,
    const unsigned short* __restrict__ w1hi, const unsigned short* __restrict__ w1lo,
    const float* __restrict__ b1,
    const unsigned short* __restrict__ w2hi, const unsigned short* __restrict__ w2lo,
    const float* __restrict__ b2,
    const unsigned short* __restrict__ w3hi, const unsigned short* __restrict__ w3lo,
    const float* __restrict__ b3,
    const unsigned short* __restrict__ w4hi, const unsigned short* __restrict__ w4lo,
    const float* __restrict__ b4,
    float* __restrict__ out)
{
    __shared__ char a_hi[16384];
    __shared__ char a_lo[16384];

    const int tid   = threadIdx.x;
    const int lane  = tid & 63;
    const int w     = tid >> 6;
    const int row0  = blockIdx.x * 64;
    const int lid   = lane & 31;
    const int khalf = lane >> 5;
    const int colw  = (w << 5) + lid;

    f32x16 acc0, acc1;

    #pragma unroll
    for (int i = 0; i < 16; ++i) { acc0[i] = 0.f; acc1[i] = 0.f; }
    stage_a_chunk(a_hi, a_lo, hb, 256, 128, nullptr, 0, 128, 0, row0, lane, w);
    __syncthreads();
    mfma_chunk(a_hi, a_lo, w1hi, w1lo, 0, 8, lid, khalf, colw, acc0, acc1);
    __syncthreads();
    {
        float bc = b1[colw];
        #pragma unroll
        for (int reg = 0; reg < 16; ++reg) {
            int rr = (reg & 3) + ((reg >> 2) << 3) + (khalf << 2);
            store_split(a_hi, a_lo, rr, colw, silu_f(acc0[reg] + bc));
            store_split(a_hi, a_lo, rr + 32, colw, silu_f(acc1[reg] + bc));
        }
    }
    __syncthreads();

    #pragma unroll
    for (int i = 0; i < 16; ++i) { acc0[i] = 0.f; acc1[i] = 0.f; }
    mfma_chunk(a_hi, a_lo, w2hi, w2lo, 0, 8, lid, khalf, colw, acc0, acc1);
    __syncthreads();
    {
        float bc = b2[colw];
        #pragma unroll
        for (int reg = 0; reg < 16; ++reg) {
            int rr = (reg & 3) + ((reg >> 2) << 3) + (khalf << 2);
            store_split(a_hi, a_lo, rr, colw, acc0[reg] + bc);
            store_split(a_hi, a_lo, rr + 32, colw, acc1[reg] + bc);
        }
    }
    __syncthreads();

    #pragma unroll
    for (int i = 0; i < 16; ++i) { acc0[i] = 0.f; acc1[i] = 0.f; }
    mfma_chunk(a_hi, a_lo, w3hi, w3lo, 0, 8, lid, khalf, colw, acc0, acc1);
    __syncthreads();
    {
        float bc = b3[colw];
        #pragma unroll
        for (int reg = 0; reg < 16; ++reg) {
            int rr = (reg & 3) + ((reg >> 2) << 3) + (khalf << 2);
            store_split(a_hi, a_lo, rr, colw, silu_f(acc0[reg] + bc));
            store_split(a_hi, a_lo, rr + 32, colw, silu_f(acc1[reg] + bc));
        }
    }
    __syncthreads();

    #pragma unroll
    for (int i = 0; i < 16; ++i) { acc0[i] = 0.f; acc1[i] = 0.f; }
    mfma_chunk(a_hi, a_lo, w4hi, w4lo, 0, 8, lid, khalf, colw, acc0, acc1);
    if (colw < NOUT) {
        float bc = b4[colw];
        #pragma unroll
        for (int reg = 0; reg < 16; ++reg) {
            int rr = (reg & 3) + ((reg >> 2) << 3) + (khalf << 2);
            out[(size_t)(row0 + rr) * NOUT + colw]      = acc0[reg] + bc;
            out[(size_t)(row0 + rr + 32) * NOUT + colw] = acc1[reg] + bc;
        }
    }
}

// ---------------- fused edge kernel (R12 known-good 64-edge structure) -----
__global__ __launch_bounds__(256) void edge_kernel(
    const float* __restrict__ P,
    const int* __restrict__ srow, const int* __restrict__ scol,
    const float* __restrict__ srad, const float* __restrict__ sea,
    const unsigned short* __restrict__ w2tb_hi,
    const unsigned short* __restrict__ w2tb_lo,
    const float* __restrict__ b2,
    const float* __restrict__ wr, const float* __restrict__ we,
    float* __restrict__ hb)
{
    __shared__ char smem[64 * 132 * 4];
    __shared__ int   s_row[64];
    __shared__ int   s_col[64];
    __shared__ float s_rad[64];
    __shared__ float s_ea4[64 * 4];
    __shared__ int   s_segstart[66];
    __shared__ int   s_nseg;

    char* a_hi = smem;
    char* a_lo = smem + 16384;
    float* s_ef = (float*)smem;

    const int tid  = threadIdx.x;
    const int lane = tid & 63;
    const int w    = tid >> 6;
    const int p0   = blockIdx.x * 64;

    if (tid < 64) {
        s_row[tid] = srow[p0 + tid];
        s_col[tid] = scol[p0 + tid];
        s_rad[tid] = srad[p0 + tid];
        *(float4*)&s_ea4[tid * 4] = *(const float4*)&sea[(size_t)(p0 + tid) * 4];
    }
    __syncthreads();

    if (tid < 64) {
        bool flag = (tid == 0) || (s_row[tid] != s_row[tid - 1]);
        unsigned long long mask = __ballot(flag);
        int idx = __popcll(mask & ((1ull << tid) - 1));
        if (flag) s_segstart[idx] = tid;
        if (tid == 0) { int ns = __popcll(mask); s_nseg = ns; s_segstart[ns] = 64; }
    }

    // phase 1: pre1 -> silu -> split bf16 -> LDS (vec2 packed math)
    const int k2 = lane * 2;
    const vf2 wrv = *(const vf2*)&wr[k2];
    const vf2 wa0 = *(const vf2*)&we[0 * 128 + k2];
    const vf2 wa1 = *(const vf2*)&we[1 * 128 + k2];
    const vf2 wa2 = *(const vf2*)&we[2 * 128 + k2];
    const vf2 wa3 = *(const vf2*)&we[3 * 128 + k2];
    #pragma unroll 4
    for (int it = 0; it < 16; ++it) {
        int et = it * 4 + w;
        int r = s_row[et], c = s_col[et];
        float rad = s_rad[et];
        float4 ea = *(const float4*)&s_ea4[et * 4];
        vf2 ps = *(const vf2*)&P[(size_t)r * 256 + k2];
        vf2 pt = *(const vf2*)&P[(size_t)c * 256 + 128 + k2];
        vf2 pre = ps + pt;
        pre += rad * wrv;
        pre += ea.x * wa0;
        pre += ea.y * wa1;
        pre += ea.z * wa2;
        pre += ea.w * wa3;
        vf2 sl;
        sl.x = silu_f(pre.x);
        sl.y = silu_f(pre.y);
        unsigned hi2, lo2;
        split2v(sl, hi2, lo2);
        int byte = (et * 256 + lane * 4) ^ ((et & 7) << 4);
        *(unsigned*)(a_hi + byte) = hi2;
        *(unsigned*)(a_lo + byte) = lo2;
    }
    __syncthreads();

    // phase 2: [64x128] @ [128x128] split-bf16 MFMA (B streamed via L1)
    const int lid   = lane & 31;
    const int khalf = lane >> 5;
    const int colw  = (w << 5) + lid;
    f32x16 acc0, acc1;
    #pragma unroll
    for (int i = 0; i < 16; ++i) { acc0[i] = 0.f; acc1[i] = 0.f; }
    mfma_chunk(a_hi, a_lo, w2tb_hi, w2tb_lo, 0, 8, lid, khalf, colw, acc0, acc1);
    __syncthreads();

    // phase 2b: silu(acc + b2) -> s_ef (f32, 132-stride)
    float bcol = b2[colw];
    #pragma unroll
    for (int reg = 0; reg < 16; ++reg) {
        int rr = (reg & 3) + ((reg >> 2) << 3) + (khalf << 2);
        s_ef[rr * 132 + colw]        = silu_f(acc0[reg] + bcol);
        s_ef[(rr + 32) * 132 + colw] = silu_f(acc1[reg] + bcol);
    }
    __syncthreads();

    // phase 3: segmented reduce; interior rows -> store, boundary -> atomics
    const int jg = tid & 31, rg = tid >> 5;
    const int j = jg * 4;
    const int nseg = s_nseg;
    for (int s = rg; s < nseg; s += 8) {
        int sp0 = s_segstart[s], sp1 = s_segstart[s + 1];
        float v0 = 0.f, v1 = 0.f, v2 = 0.f, v3 = 0.f;
        for (int p = sp0; p < sp1; ++p) {
            float4 q = *(const float4*)&s_ef[p * 132 + j];
            v0 += q.x; v1 += q.y; v2 += q.z; v3 += q.w;
        }
        int rowId = s_row[sp0];
        bool interior = true;
        if (sp0 == 0 && p0 > 0 && srow[p0 - 1] == rowId) interior = false;
        if (sp1 == 64 && p0 + 64 < N_EDGES && srow[p0 + 64] == rowId) interior = false;
        float* dst = &hb[(size_t)rowId * 256 + 128 + j];
        if (interior) {
            *(float4*)dst = make_float4(v0, v1, v2, v3);
        } else {
            atomicAdd(&dst[0], v0); atomicAdd(&dst[1], v1);
            atomicAdd(&dst[2], v2); atomicAdd(&dst[3], v3);
        }
    }
}

extern "C" void kernel_launch(void* const* d_in, const int* in_sizes, int n_in,
                              void* d_out, int out_size, void* d_ws, size_t ws_size,
                              hipStream_t stream)
{
    const float* h0       = (const float*)d_in[0];
    const float* x        = (const float*)d_in[1];
    const int*   edges    = (const int*)  d_in[2];
    const float* edge_attr= (const float*)d_in[3];
    const float* emb_w    = (const float*)d_in[4];
    const float* emb_b    = (const float*)d_in[5];
    const float* ew1      = (const float*)d_in[6];
    const float* eb1      = (const float*)d_in[7];
    const float* ew2      = (const float*)d_in[8];
    const float* eb2      = (const float*)d_in[9];
    const float* nw1      = (const float*)d_in[10];
    const float* nb1      = (const float*)d_in[11];
    const float* nw2      = (const float*)d_in[12];
    const float* nb2      = (const float*)d_in[13];
    const float* dw1      = (const float*)d_in[14];
    const float* db1      = (const float*)d_in[15];
    const float* dw2      = (const float*)d_in[16];
    const float* db2      = (const float*)d_in[17];
    const float* gw1      = (const float*)d_in[18];
    const float* gb1      = (const float*)d_in[19];
    const float* gw2      = (const float*)d_in[20];
    const float* gb2      = (const float*)d_in[21];
    float* out = (float*)d_out;

    char* ws = (char*)d_ws;
    const size_t SZ_HB = (size_t)N_NODES * 256 * 4;
    const size_t SZ_T  = (size_t)N_NODES * HID * 4;
    const size_t SZ_E  = (size_t)N_EDGES * 4;
    float* hb     = (float*)(ws);                       // [N,256] = [h | agg]
    float* P      = (float*)(ws + SZ_HB);               // [N,256]
    char*  base   = ws + SZ_HB * 2 + SZ_T;
    // base region: [w_hi/w_lo (1.88 MB, fits in SZ_E slot)] [s_row..] etc.
    int*   s_row  = (int*)  (base + SZ_E);
    int*   s_col  = (int*)  (base + SZ_E * 2);
    float* s_rad  = (float*)(base + SZ_E * 3);
    float* s_ea   = (float*)(base + SZ_E * 4);
    int*   rowptr = (int*)  (base + SZ_E * 8);
    int*   cnt    = (int*)  (base + SZ_E * 8 + (N_NODES + 64) * 4);
    int*   incl   = (int*)  (base + SZ_E * 8 + (N_NODES + 64) * 8);
    int*   bsum   = (int*)  (base + SZ_E * 8 + (N_NODES + 64) * 12);
    int*   boff   = bsum + 64;
    unsigned short* w_hi = (unsigned short*)base;
    unsigned short* w_lo = w_hi + W_TOTAL;

    const int* erow = edges;
    const int* ecol = edges + N_EDGES;

    // CSR build (edges constant across layers); radial fused into scatter
    hipMemsetAsync(cnt, 0, N_NODES * 4, stream);
    hist_kernel<<<N_EDGES / 256, 256, 0, stream>>>(erow, cnt);
    scan1_kernel<<<40, 1024, 0, stream>>>(cnt, incl, bsum);   // also zeroes cnt
    scan2_kernel<<<1, 64, 0, stream>>>(bsum, boff, rowptr);
    scan3_kernel<<<40, 1024, 0, stream>>>(incl, boff, rowptr);
    scatter_kernel<<<N_EDGES / 256, 256, 0, stream>>>(
        x, erow, ecol, edge_attr, rowptr, cnt, s_row, s_col, s_rad, s_ea);

    prep_all_kernel<<<dim3(136, 25), 256, 0, stream>>>(
        ew1, ew2, nw1, nw2, dw1, dw2, gw1, emb_w, gw2, w_hi, w_lo);

    // fused: h = h0@emb_w+emb_b ; layer-0 projection ; agg zero
    emb_proj_kernel<<<625, 256, 0, stream>>>(
        h0, w_hi + OFF_EMB, w_lo + OFF_EMB, emb_b,
        w_hi + OFF_W1A, w_lo + OFF_W1A, w_hi + OFF_W1B, w_lo + OFF_W1B,
        eb1, hb, P);

    for (int l = 0; l < NLAYERS; ++l) {
        const float* W1   = ew1 + (size_t)l * 261 * 128;
        const float* b2v  = eb2 + l * 128;
        const float* nb1v = nb1 + l * 128;
        const float* nb2v = nb2 + l * 128;

        edge_kernel<<<N_EDGES / 64, 256, 0, stream>>>(
            P, s_row, s_col, s_rad, s_ea,
            w_hi + OFF_W2 + (size_t)l * 16384, w_lo + OFF_W2 + (size_t)l * 16384,
            b2v, W1 + 256 * 128, W1 + 257 * 128, hb);

        if (l < NLAYERS - 1) {
            chain3_node_kernel<<<625, 256, 0, stream>>>(
                hb, h0,
                w_hi + OFF_NW1 + l * 34816, w_lo + OFF_NW1 + l * 34816, nb1v,
                w_hi + OFF_NW2 + l * 16384, w_lo + OFF_NW2 + l * 16384, nb2v,
                w_hi + OFF_W1A + (l + 1) * 16384, w_lo + OFF_W1A + (l + 1) * 16384,
                w_hi + OFF_W1B + (l + 1) * 16384, w_lo + OFF_W1B + (l + 1) * 16384,
                eb1 + (l + 1) * 128,
                hb, P);
        } else {
            mfma_chain2_kernel<<<625, 256, 0, stream>>>(
                hb, 256, 256, h0, F_IN, 271,
                w_hi + OFF_NW1 + l * 34816, w_lo + OFF_NW1 + l * 34816,
                nb1v, FLAG_BIAS | FLAG_SILU,
                w_hi + OFF_NW2 + l * 16384, w_lo + OFF_NW2 + l * 16384,
                nb2v, FLAG_BIAS | FLAG_ACC,
                hb, 256);
        }
    }

    // decoder: all four GEMMs in one kernel, writes out[N,21] directly
    chain4_dec_kernel<<<625, 256, 0, stream>>>(
        hb,
        w_hi + OFF_DW1, w_lo + OFF_DW1, db1,
        w_hi + OFF_DW2, w_lo + OFF_DW2, db2,
        w_hi + OFF_GW1, w_lo + OFF_GW1, gb1,
        w_hi + OFF_GW2, w_lo + OFF_GW2, gb2,
        out);
}